// Round 1
// baseline (600.730 us; speedup 1.0000x reference)
//
#include <hip/hip_runtime.h>
#include <hip/hip_bf16.h>

#define N_NODES 4096
#define HID 512
#define HEADS 8
#define DH 64
#define EPS 1e-5f
#define MAXD 128

// ---------------------------------------------------------------------------
// Generic fp32 tiled GEMM: C[M x Nc] = X[M x K] @ W[K x Nc] (+bias)(+relu/res)
// 64x64 block tile, BK=16, 256 threads, 4x4 microtile per thread.
// epi: 0 = bias, 1 = bias+relu, 2 = bias+residual
// ---------------------------------------------------------------------------
__global__ __launch_bounds__(256) void gemm_f32(
    const float* __restrict__ X, const float* __restrict__ W,
    const float* __restrict__ bias, const float* __restrict__ res,
    float* __restrict__ C, int M, int K, int Nc, int epi)
{
    __shared__ __align__(16) float As[16][68];  // [k][m], pad 68 -> 16B-aligned float4 rows, conflict-free
    __shared__ __align__(16) float Bs[16][64];  // [k][n]

    const int tid = threadIdx.x;
    const int tx = tid & 15;        // micro col group (0..15)
    const int ty = tid >> 4;        // micro row group (0..15)
    const int n0 = blockIdx.x * 64;
    const int m0 = blockIdx.y * 64;

    float acc[4][4] = {};

    for (int k0 = 0; k0 < K; k0 += 16) {
        // A tile: X[m0..+64)[k0..+16) stored transposed As[k][m]
        #pragma unroll
        for (int p = 0; p < 4; ++p) {
            int r = ty + p * 16;
            As[tx][r] = X[(size_t)(m0 + r) * K + k0 + tx];
        }
        // B tile: W[k0..+16)[n0..+64)
        {
            int c2 = tid & 63, r2 = tid >> 6;   // r2 0..3
            #pragma unroll
            for (int p = 0; p < 4; ++p) {
                Bs[r2 + p * 4][c2] = W[(size_t)(k0 + r2 + p * 4) * Nc + n0 + c2];
            }
        }
        __syncthreads();
        #pragma unroll
        for (int kk = 0; kk < 16; ++kk) {
            float4 a = *(const float4*)&As[kk][ty * 4];
            float4 b = *(const float4*)&Bs[kk][tx * 4];
            acc[0][0] += a.x * b.x; acc[0][1] += a.x * b.y; acc[0][2] += a.x * b.z; acc[0][3] += a.x * b.w;
            acc[1][0] += a.y * b.x; acc[1][1] += a.y * b.y; acc[1][2] += a.y * b.z; acc[1][3] += a.y * b.w;
            acc[2][0] += a.z * b.x; acc[2][1] += a.z * b.y; acc[2][2] += a.z * b.z; acc[2][3] += a.z * b.w;
            acc[3][0] += a.w * b.x; acc[3][1] += a.w * b.y; acc[3][2] += a.w * b.z; acc[3][3] += a.w * b.w;
        }
        __syncthreads();
    }

    #pragma unroll
    for (int i = 0; i < 4; ++i) {
        int m = m0 + ty * 4 + i;
        #pragma unroll
        for (int j = 0; j < 4; ++j) {
            int n = n0 + tx * 4 + j;
            float v = acc[i][j] + bias[n];
            if (epi == 1) v = fmaxf(v, 0.0f);
            else if (epi == 2) v += res[(size_t)m * Nc + n];
            C[(size_t)m * Nc + n] = v;
        }
    }
}

// ---------------------------------------------------------------------------
// Adjacency compaction: one wave per row, ballot-based ordered compaction.
// ---------------------------------------------------------------------------
__global__ __launch_bounds__(256) void build_adj(
    const float* __restrict__ A, int* __restrict__ idx, int* __restrict__ deg)
{
    int wave = (blockIdx.x * 256 + threadIdx.x) >> 6;
    int lane = threadIdx.x & 63;
    if (wave >= N_NODES) return;
    const float* row = A + (size_t)wave * N_NODES;
    int base = 0;
    for (int c0 = 0; c0 < N_NODES; c0 += 64) {
        float v = row[c0 + lane];
        unsigned long long m = __ballot(v > 0.0f);
        int before = __popcll(m & ((1ull << lane) - 1ull));
        if (v > 0.0f) {
            int p = base + before;
            if (p < MAXD) idx[wave * MAXD + p] = c0 + lane;
        }
        base += __popcll(m);
    }
    if (lane == 0) deg[wave] = base < MAXD ? base : MAXD;
}

// ---------------------------------------------------------------------------
// Sparse masked attention. One block per node (4 waves); each wave does 2
// heads. Lane = head dim. Scores via 64-lane shuffle reduce; exact softmax
// (masked entries contribute exactly 0, identical to the dense reference).
// ---------------------------------------------------------------------------
__global__ __launch_bounds__(256) void sparse_attn(
    const float* __restrict__ q, const float* __restrict__ k,
    const float* __restrict__ v, const int* __restrict__ idx,
    const int* __restrict__ deg, float* __restrict__ o)
{
    const int n = blockIdx.x;
    const int tid = threadIdx.x;
    const int wv = tid >> 6, lane = tid & 63;

    __shared__ int s_idx[MAXD];
    __shared__ float s_sc[4][MAXD];

    const int d = deg[n];
    for (int i = tid; i < d; i += 256) s_idx[i] = idx[n * MAXD + i];
    __syncthreads();

    for (int h = wv; h < HEADS; h += 4) {
        const float qd = q[(size_t)n * HID + h * DH + lane];
        // scores
        for (int j = 0; j < d; ++j) {
            int m = s_idx[j];
            float s = qd * k[(size_t)m * HID + h * DH + lane];
            #pragma unroll
            for (int off = 32; off; off >>= 1) s += __shfl_xor(s, off);
            if (lane == 0) s_sc[wv][j] = s * 0.125f;   // 1/sqrt(64)
        }
        // softmax (max, exp, sum)
        float mx = -1e30f;
        for (int j = lane; j < d; j += 64) mx = fmaxf(mx, s_sc[wv][j]);
        #pragma unroll
        for (int off = 32; off; off >>= 1) mx = fmaxf(mx, __shfl_xor(mx, off));
        float sum = 0.0f;
        for (int j = lane; j < d; j += 64) {
            float e = __expf(s_sc[wv][j] - mx);
            s_sc[wv][j] = e;
            sum += e;
        }
        #pragma unroll
        for (int off = 32; off; off >>= 1) sum += __shfl_xor(sum, off);
        float inv = 1.0f / sum;
        // o = sum_j p_j * v[m_j]
        float acc = 0.0f;
        for (int j = 0; j < d; ++j) {
            acc += s_sc[wv][j] * v[(size_t)s_idx[j] * HID + h * DH + lane];
        }
        o[(size_t)n * HID + h * DH + lane] = acc * inv;
    }
}

// ---------------------------------------------------------------------------
// BatchNorm column stats: 512 threads (one per column), 32 rows per block,
// atomicAdd partials into zeroed accumulators.
// ---------------------------------------------------------------------------
__global__ __launch_bounds__(512) void colstats(
    const float* __restrict__ x, float* __restrict__ sum, float* __restrict__ sumsq)
{
    const int c = threadIdx.x;
    const int r0 = blockIdx.x * 32;
    float s = 0.0f, ss = 0.0f;
    for (int r = 0; r < 32; ++r) {
        float v = x[(size_t)(r0 + r) * HID + c];
        s += v; ss += v * v;
    }
    atomicAdd(&sum[c], s);
    atomicAdd(&sumsq[c], ss);
}

__global__ __launch_bounds__(256) void bn_apply(
    const float* __restrict__ x, const float* __restrict__ sum,
    const float* __restrict__ sumsq, const float* __restrict__ g,
    const float* __restrict__ b, float* __restrict__ y)
{
    const int i = blockIdx.x * 256 + threadIdx.x;
    const int c = i & (HID - 1);
    const float m = sum[c] * (1.0f / N_NODES);
    const float var = sumsq[c] * (1.0f / N_NODES) - m * m;
    const float inv = rsqrtf(var + EPS);
    y[i] = g[c] * (x[i] - m) * inv + b[c];
}

// ---------------------------------------------------------------------------

extern "C" void kernel_launch(void* const* d_in, const int* in_sizes, int n_in,
                              void* d_out, int out_size, void* d_ws, size_t ws_size,
                              hipStream_t stream)
{
    const float* A   = (const float*)d_in[0];
    const float* h   = (const float*)d_in[1];
    const float* Wq  = (const float*)d_in[2];
    const float* bq  = (const float*)d_in[3];
    const float* Wk  = (const float*)d_in[4];
    const float* bk  = (const float*)d_in[5];
    const float* Wv  = (const float*)d_in[6];
    const float* bv  = (const float*)d_in[7];
    const float* Wo  = (const float*)d_in[8];
    const float* bo  = (const float*)d_in[9];
    const float* g1  = (const float*)d_in[10];
    const float* b1g = (const float*)d_in[11];
    const float* g2  = (const float*)d_in[12];
    const float* b2g = (const float*)d_in[13];
    const float* W1  = (const float*)d_in[14];
    const float* b1  = (const float*)d_in[15];
    const float* W2  = (const float*)d_in[16];
    const float* b2  = (const float*)d_in[17];
    float* out = (float*)d_out;

    const size_t NH = (size_t)N_NODES * HID;       // 2,097,152
    float* ws = (float*)d_ws;
    float* q    = ws;
    float* k    = ws + NH;
    float* v    = ws + 2 * NH;
    float* o    = ws + 3 * NH;
    float* x1   = ws + 4 * NH;
    float* xb1  = ws + 5 * NH;
    float* t    = ws + 6 * NH;                      // 4096 x 1024 (2*NH floats)
    float* x2   = ws + 8 * NH;
    float* st   = ws + 9 * NH;                      // sum1|sumsq1|sum2|sumsq2 (4*512)
    int*   adj  = (int*)(ws + 9 * NH + 4 * HID);
    int*   deg  = adj + N_NODES * MAXD;

    dim3 blk256(256), blk512(512);

    // QKV projections
    gemm_f32<<<dim3(HID / 64, N_NODES / 64), blk256, 0, stream>>>(h, Wq, bq, nullptr, q, N_NODES, HID, HID, 0);
    gemm_f32<<<dim3(HID / 64, N_NODES / 64), blk256, 0, stream>>>(h, Wk, bk, nullptr, k, N_NODES, HID, HID, 0);
    gemm_f32<<<dim3(HID / 64, N_NODES / 64), blk256, 0, stream>>>(h, Wv, bv, nullptr, v, N_NODES, HID, HID, 0);

    // Adjacency compaction (one wave per row)
    build_adj<<<dim3(N_NODES / 4), blk256, 0, stream>>>(A, adj, deg);

    // Sparse masked attention
    sparse_attn<<<dim3(N_NODES), blk256, 0, stream>>>(q, k, v, adj, deg, o);

    // O projection + residual:  x1 = h + o @ Wo + bo
    gemm_f32<<<dim3(HID / 64, N_NODES / 64), blk256, 0, stream>>>(o, Wo, bo, h, x1, N_NODES, HID, HID, 2);

    // BN1
    hipMemsetAsync(st, 0, 4 * HID * sizeof(float), stream);
    colstats<<<dim3(N_NODES / 32), blk512, 0, stream>>>(x1, st, st + HID);
    bn_apply<<<dim3(NH / 256), blk256, 0, stream>>>(x1, st, st + HID, g1, b1g, xb1);

    // FFN
    gemm_f32<<<dim3(2 * HID / 64, N_NODES / 64), blk256, 0, stream>>>(xb1, W1, b1, nullptr, t, N_NODES, HID, 2 * HID, 1);
    gemm_f32<<<dim3(HID / 64, N_NODES / 64), blk256, 0, stream>>>(t, W2, b2, xb1, x2, N_NODES, 2 * HID, HID, 2);

    // BN2 -> out
    colstats<<<dim3(N_NODES / 32), blk512, 0, stream>>>(x2, st + 2 * HID, st + 3 * HID);
    bn_apply<<<dim3(NH / 256), blk256, 0, stream>>>(x2, st + 2 * HID, st + 3 * HID, g2, b2g, out);

    (void)in_sizes; (void)n_in; (void)out_size; (void)ws_size;
}

// Round 2
// 383.034 us; speedup vs baseline: 1.5683x; 1.5683x over previous
//
#include <hip/hip_runtime.h>

#define N_NODES 4096
#define HID 512
#define HEADS 8
#define DH 64
#define EPS 1e-5f
#define MAXD 128

typedef __attribute__((ext_vector_type(8))) short bf16x8;
typedef __attribute__((ext_vector_type(4))) float f32x4;

__device__ __forceinline__ unsigned short f2bf(float f) {
    unsigned int u = __float_as_uint(f);
    unsigned int r = (u + 0x7FFFu + ((u >> 16) & 1u)) >> 16;   // RNE
    return (unsigned short)r;
}
__device__ __forceinline__ float bf2f(unsigned short u) {
    return __uint_as_float(((unsigned int)u) << 16);
}

__device__ __forceinline__ void gld_lds16(const void* g, void* l) {
    __builtin_amdgcn_global_load_lds(
        (const __attribute__((address_space(1))) unsigned int*)g,
        (__attribute__((address_space(3))) unsigned int*)l, 16, 0, 0);
}

// ---------------------------------------------------------------------------
// bf16 MFMA GEMM: C[M x Nc] = X[M x K] @ W^T  (W pre-transposed: Wt[Nc][K])
// 128x128 tile, BK=32, 256 threads = 4 waves (2x2), 4x4 16x16x32 MFMA each.
// epi: 0 = bias -> bf16 out ; 1 = bias+relu -> bf16 out ; 2 = bias+res -> f32
// ---------------------------------------------------------------------------
__global__ __launch_bounds__(256) void gemm_bf16(
    const unsigned short* __restrict__ Xb, const unsigned short* __restrict__ Wt,
    const float* __restrict__ bias, const float* __restrict__ res,
    float* __restrict__ outf, unsigned short* __restrict__ outb,
    int K, int Nc, int epi)
{
    __shared__ __align__(16) unsigned short As[128 * 32];
    __shared__ __align__(16) unsigned short Bs[128 * 32];

    const int tid = threadIdx.x;
    const int lane = tid & 63;
    const int wv = tid >> 6;
    const int wm = wv >> 1, wn = wv & 1;
    const int m0 = blockIdx.y * 128, n0 = blockIdx.x * 128;

    const int rowA = tid >> 2;            // 0..63 (pass 2 adds 64)
    const int kof = (tid & 3) * 8;        // k offset in elements
    unsigned short* ldsA = As + tid * 8;  // == row*32 + kof (contiguous per wave)
    unsigned short* ldsB = Bs + tid * 8;

    f32x4 acc[4][4] = {};
    const int lc = lane & 15, lq = lane >> 4;

    for (int k0 = 0; k0 < K; k0 += 32) {
        const unsigned short* gA = Xb + (size_t)(m0 + rowA) * K + k0 + kof;
        const unsigned short* gB = Wt + (size_t)(n0 + rowA) * K + k0 + kof;
        gld_lds16(gA, ldsA);
        gld_lds16(gA + (size_t)64 * K, ldsA + 2048);
        gld_lds16(gB, ldsB);
        gld_lds16(gB + (size_t)64 * K, ldsB + 2048);
        __syncthreads();

        bf16x8 af[4], bfr[4];
        #pragma unroll
        for (int i = 0; i < 4; ++i)
            af[i] = *(const bf16x8*)&As[(wm * 64 + i * 16 + lc) * 32 + lq * 8];
        #pragma unroll
        for (int j = 0; j < 4; ++j)
            bfr[j] = *(const bf16x8*)&Bs[(wn * 64 + j * 16 + lc) * 32 + lq * 8];
        #pragma unroll
        for (int i = 0; i < 4; ++i)
            #pragma unroll
            for (int j = 0; j < 4; ++j)
                acc[i][j] = __builtin_amdgcn_mfma_f32_16x16x32_bf16(af[i], bfr[j], acc[i][j], 0, 0, 0);
        __syncthreads();
    }

    #pragma unroll
    for (int i = 0; i < 4; ++i) {
        #pragma unroll
        for (int j = 0; j < 4; ++j) {
            const int gr0 = m0 + wm * 64 + i * 16 + lq * 4;
            const int gc = n0 + wn * 64 + j * 16 + lc;
            const float bi = bias[gc];
            #pragma unroll
            for (int r = 0; r < 4; ++r) {
                float val = acc[i][j][r] + bi;
                size_t off = (size_t)(gr0 + r) * Nc + gc;
                if (epi == 0)      outb[off] = f2bf(val);
                else if (epi == 1) outb[off] = f2bf(fmaxf(val, 0.f));
                else               outf[off] = val + res[off];
            }
        }
    }
}

// ---------------------------------------------------------------------------
// Prep kernels
// ---------------------------------------------------------------------------
__global__ __launch_bounds__(256) void conv_bf16(
    const float* __restrict__ in, unsigned short* __restrict__ out, int n)
{
    int i = blockIdx.x * 256 + threadIdx.x;
    if (i < n) out[i] = f2bf(in[i]);
}

// in [R][C] fp32 -> out [C][R] bf16
__global__ __launch_bounds__(256) void transpose_to_bf16(
    const float* __restrict__ in, unsigned short* __restrict__ out, int R, int C)
{
    __shared__ float tile[32][33];
    const int bc = blockIdx.x * 32, br = blockIdx.y * 32;
    const int tx = threadIdx.x & 31, ty = threadIdx.x >> 5;  // ty 0..7
    #pragma unroll
    for (int r = ty; r < 32; r += 8)
        tile[r][tx] = in[(size_t)(br + r) * C + bc + tx];
    __syncthreads();
    #pragma unroll
    for (int r = ty; r < 32; r += 8)
        out[(size_t)(bc + r) * R + br + tx] = f2bf(tile[tx][r]);
}

__global__ __launch_bounds__(256) void concat_bias(
    const float* __restrict__ bq, const float* __restrict__ bk,
    const float* __restrict__ bv, float* __restrict__ out)
{
    int i = blockIdx.x * 256 + threadIdx.x;
    out[i] = i < 512 ? bq[i] : (i < 1024 ? bk[i - 512] : bv[i - 1024]);
}

// ---------------------------------------------------------------------------
// Adjacency compaction: one wave per row, ballot-based ordered compaction.
// ---------------------------------------------------------------------------
__global__ __launch_bounds__(256) void build_adj(
    const float* __restrict__ A, int* __restrict__ idx, int* __restrict__ deg)
{
    int wave = (blockIdx.x * 256 + threadIdx.x) >> 6;
    int lane = threadIdx.x & 63;
    if (wave >= N_NODES) return;
    const float* row = A + (size_t)wave * N_NODES;
    int base = 0;
    for (int c0 = 0; c0 < N_NODES; c0 += 64) {
        float v = row[c0 + lane];
        unsigned long long m = __ballot(v > 0.0f);
        int before = __popcll(m & ((1ull << lane) - 1ull));
        if (v > 0.0f) {
            int p = base + before;
            if (p < MAXD) idx[wave * MAXD + p] = c0 + lane;
        }
        base += __popcll(m);
    }
    if (lane == 0) deg[wave] = base < MAXD ? base : MAXD;
}

// ---------------------------------------------------------------------------
// Sparse attention v2 on bf16 fused qkv [N][1536] (q|k|v, head-major).
// Block = node, 4 waves; wave handles heads wv and wv+4.
// Score phase: 4 neighbors/iter (16 lanes x 4 dims each, 4-shuffle reduce).
// Accum phase: 2 neighbors x 2-dim pairs per lane, x2 unrolled.
// ---------------------------------------------------------------------------
__global__ __launch_bounds__(256) void sparse_attn2(
    const unsigned short* __restrict__ qkv, const int* __restrict__ idx,
    const int* __restrict__ deg, unsigned short* __restrict__ o)
{
    const int n = blockIdx.x;
    const int tid = threadIdx.x;
    const int wv = tid >> 6, lane = tid & 63;

    __shared__ int s_idx[MAXD];
    __shared__ float s_p[4][MAXD];

    const int d = deg[n];
    for (int i = tid; i < d; i += 256) s_idx[i] = idx[n * MAXD + i];
    __syncthreads();

    const unsigned int* q32 = (const unsigned int*)qkv;  // dword = 2 bf16
    const int jl = lane >> 4;        // neighbor sub-index 0..3 (score phase)
    const int dg = lane & 15;        // dim group (4 dims)
    const int half = lane >> 5, l2 = lane & 31;

    for (int hp = 0; hp < 2; ++hp) {
        const int h = wv + hp * 4;
        const int qbase = n * 768 + h * 32;
        uint2 qw = *(const uint2*)(q32 + qbase + dg * 2);
        float q0 = bf2f(qw.x & 0xffff), q1 = bf2f(qw.x >> 16);
        float q2 = bf2f(qw.y & 0xffff), q3 = bf2f(qw.y >> 16);

        for (int j0 = 0; j0 < d; j0 += 4) {
            int jj = j0 + jl;
            float s = 0.f;
            if (jj < d) {
                int m = s_idx[jj];
                uint2 kw = *(const uint2*)(q32 + m * 768 + 256 + h * 32 + dg * 2);
                s = q0 * bf2f(kw.x & 0xffff) + q1 * bf2f(kw.x >> 16)
                  + q2 * bf2f(kw.y & 0xffff) + q3 * bf2f(kw.y >> 16);
            }
            s += __shfl_xor(s, 1);
            s += __shfl_xor(s, 2);
            s += __shfl_xor(s, 4);
            s += __shfl_xor(s, 8);
            if (dg == 0 && jj < d) s_p[wv][jj] = s * 0.125f;  // 1/sqrt(64)
        }

        // softmax over s_p[wv][0..d)
        float mx = -1e30f;
        for (int j = lane; j < d; j += 64) mx = fmaxf(mx, s_p[wv][j]);
        #pragma unroll
        for (int off = 32; off; off >>= 1) mx = fmaxf(mx, __shfl_xor(mx, off));
        float sum = 0.f;
        for (int j = lane; j < d; j += 64) {
            float e = __expf(s_p[wv][j] - mx);
            s_p[wv][j] = e;
            sum += e;
        }
        #pragma unroll
        for (int off = 32; off; off >>= 1) sum += __shfl_xor(sum, off);
        const float inv = 1.0f / sum;

        // o accumulate
        const int vbase = 512 + h * 32 + l2;
        float ax = 0.f, ay = 0.f;
        for (int j0 = 0; j0 < d; j0 += 4) {
            int ja = j0 + half, jb = j0 + 2 + half;
            if (ja < d) {
                unsigned int vw = q32[s_idx[ja] * 768 + vbase];
                float p = s_p[wv][ja];
                ax += p * bf2f(vw & 0xffff);
                ay += p * bf2f(vw >> 16);
            }
            if (jb < d) {
                unsigned int vw = q32[s_idx[jb] * 768 + vbase];
                float p = s_p[wv][jb];
                ax += p * bf2f(vw & 0xffff);
                ay += p * bf2f(vw >> 16);
            }
        }
        ax += __shfl_xor(ax, 32);
        ay += __shfl_xor(ay, 32);
        if (half == 0) {
            unsigned int pack = (unsigned int)f2bf(ax * inv)
                              | ((unsigned int)f2bf(ay * inv) << 16);
            ((unsigned int*)o)[n * 256 + h * 32 + l2] = pack;
        }
    }
}

// ---------------------------------------------------------------------------
// BatchNorm
// ---------------------------------------------------------------------------
__global__ __launch_bounds__(512) void colstats(
    const float* __restrict__ x, float* __restrict__ sum, float* __restrict__ sumsq)
{
    const int c = threadIdx.x;
    const int r0 = blockIdx.x * 32;
    float s = 0.0f, ss = 0.0f;
    for (int r = 0; r < 32; ++r) {
        float v = x[(size_t)(r0 + r) * HID + c];
        s += v; ss += v * v;
    }
    atomicAdd(&sum[c], s);
    atomicAdd(&sumsq[c], ss);
}

__global__ __launch_bounds__(256) void bn_apply(
    const float* __restrict__ x, const float* __restrict__ sum,
    const float* __restrict__ sumsq, const float* __restrict__ g,
    const float* __restrict__ b, float* __restrict__ yf,
    unsigned short* __restrict__ yb)
{
    const int i = blockIdx.x * 256 + threadIdx.x;
    const int c = i & (HID - 1);
    const float m = sum[c] * (1.0f / N_NODES);
    const float var = sumsq[c] * (1.0f / N_NODES) - m * m;
    const float inv = rsqrtf(var + EPS);
    const float val = g[c] * (x[i] - m) * inv + b[c];
    yf[i] = val;
    if (yb) yb[i] = f2bf(val);
}

// ---------------------------------------------------------------------------

extern "C" void kernel_launch(void* const* d_in, const int* in_sizes, int n_in,
                              void* d_out, int out_size, void* d_ws, size_t ws_size,
                              hipStream_t stream)
{
    const float* A   = (const float*)d_in[0];
    const float* h   = (const float*)d_in[1];
    const float* Wq  = (const float*)d_in[2];
    const float* bq  = (const float*)d_in[3];
    const float* Wk  = (const float*)d_in[4];
    const float* bk  = (const float*)d_in[5];
    const float* Wv  = (const float*)d_in[6];
    const float* bv  = (const float*)d_in[7];
    const float* Wo  = (const float*)d_in[8];
    const float* bo  = (const float*)d_in[9];
    const float* g1  = (const float*)d_in[10];
    const float* b1g = (const float*)d_in[11];
    const float* g2  = (const float*)d_in[12];
    const float* b2g = (const float*)d_in[13];
    const float* W1  = (const float*)d_in[14];
    const float* b1  = (const float*)d_in[15];
    const float* W2  = (const float*)d_in[16];
    const float* b2  = (const float*)d_in[17];
    float* out = (float*)d_out;

    float* ws = (float*)d_ws;
    unsigned short* hb    = (unsigned short*)(ws);               // 4096x512 bf16
    unsigned short* qkvb  = (unsigned short*)(ws + 1048576);     // 4096x1536 bf16
    unsigned short* o_bf  = (unsigned short*)(ws + 4194304);     // 4096x512 bf16
    unsigned short* wqkvT = (unsigned short*)(ws + 5242880);     // 1536x512 bf16
    unsigned short* woT   = (unsigned short*)(ws + 5636096);     // 512x512 bf16
    unsigned short* w1T   = (unsigned short*)(ws + 5767168);     // 1024x512 bf16
    unsigned short* w2T   = (unsigned short*)(ws + 6029312);     // 512x1024 bf16
    unsigned short* t_b   = (unsigned short*)(ws + 6291456);     // 4096x1024 bf16
    float* x1   = ws + 8388608;                                   // 4096x512 f32
    float* x2   = ws + 10485760;                                  // 4096x512 f32
    unsigned short* xb1_b = (unsigned short*)(ws + 12582912);    // 4096x512 bf16
    float* bqkv = ws + 13631488;                                  // 1536
    float* st   = ws + 13633024;                                  // 2048
    int*   adj  = (int*)(ws + 13635072);                          // 4096x128
    int*   deg  = adj + N_NODES * MAXD;

    // --- prep: conversions / transposes / bias concat / adjacency ---
    hipMemsetAsync(st, 0, 2048 * sizeof(float), stream);
    conv_bf16<<<dim3(8192), dim3(256), 0, stream>>>(h, hb, N_NODES * HID);
    transpose_to_bf16<<<dim3(16, 16), dim3(256), 0, stream>>>(Wq, wqkvT, 512, 512);
    transpose_to_bf16<<<dim3(16, 16), dim3(256), 0, stream>>>(Wk, wqkvT + 262144, 512, 512);
    transpose_to_bf16<<<dim3(16, 16), dim3(256), 0, stream>>>(Wv, wqkvT + 524288, 512, 512);
    transpose_to_bf16<<<dim3(16, 16), dim3(256), 0, stream>>>(Wo, woT, 512, 512);
    transpose_to_bf16<<<dim3(32, 16), dim3(256), 0, stream>>>(W1, w1T, 512, 1024);
    transpose_to_bf16<<<dim3(16, 32), dim3(256), 0, stream>>>(W2, w2T, 1024, 512);
    concat_bias<<<dim3(6), dim3(256), 0, stream>>>(bq, bk, bv, bqkv);
    build_adj<<<dim3(N_NODES / 4), dim3(256), 0, stream>>>(A, adj, deg);

    // --- fused QKV projection: [4096x512] @ [512x1536] -> bf16 qkv ---
    gemm_bf16<<<dim3(12, 32), dim3(256), 0, stream>>>(
        hb, wqkvT, bqkv, nullptr, nullptr, qkvb, 512, 1536, 0);

    // --- sparse masked attention ---
    sparse_attn2<<<dim3(N_NODES), dim3(256), 0, stream>>>(qkvb, adj, deg, o_bf);

    // --- O projection + residual: x1 = h + o @ Wo + bo ---
    gemm_bf16<<<dim3(4, 32), dim3(256), 0, stream>>>(
        o_bf, woT, bo, h, x1, nullptr, 512, 512, 2);

    // --- BN1 (in-place fp32 + bf16 copy for FFN) ---
    colstats<<<dim3(128), dim3(512), 0, stream>>>(x1, st, st + 512);
    bn_apply<<<dim3(8192), dim3(256), 0, stream>>>(x1, st, st + 512, g1, b1g, x1, xb1_b);

    // --- FFN ---
    gemm_bf16<<<dim3(8, 32), dim3(256), 0, stream>>>(
        xb1_b, w1T, b1, nullptr, nullptr, t_b, 512, 1024, 1);
    gemm_bf16<<<dim3(4, 32), dim3(256), 0, stream>>>(
        t_b, w2T, b2, x1, x2, nullptr, 1024, 512, 2);

    // --- BN2 -> out ---
    colstats<<<dim3(128), dim3(512), 0, stream>>>(x2, st + 1024, st + 1536);
    bn_apply<<<dim3(8192), dim3(256), 0, stream>>>(x2, st + 1024, st + 1536, g2, b2g, out, nullptr);

    (void)in_sizes; (void)n_in; (void)out_size; (void)ws_size;
}

// Round 3
// 367.654 us; speedup vs baseline: 1.6340x; 1.0418x over previous
//
#include <hip/hip_runtime.h>

#define N_NODES 4096
#define HID 512
#define HEADS 8
#define DH 64
#define EPS 1e-5f
#define MAXD 128
#define STAGE 64

typedef __attribute__((ext_vector_type(8))) short bf16x8;
typedef __attribute__((ext_vector_type(4))) float f32x4;

__device__ __forceinline__ unsigned short f2bf(float f) {
    unsigned int u = __float_as_uint(f);
    unsigned int r = (u + 0x7FFFu + ((u >> 16) & 1u)) >> 16;   // RNE
    return (unsigned short)r;
}
__device__ __forceinline__ float bf2f(unsigned short u) {
    return __uint_as_float(((unsigned int)u) << 16);
}

__device__ __forceinline__ void gld_lds16(const void* g, void* l) {
    __builtin_amdgcn_global_load_lds(
        (const __attribute__((address_space(1))) unsigned int*)g,
        (__attribute__((address_space(3))) unsigned int*)l, 16, 0, 0);
}

// ---------------------------------------------------------------------------
// bf16 MFMA GEMM: C[M x Nc] = X[M x K] @ W^T  (Wt[Nc][K] K-major)
// 128xBN tile (BN=128: 4 waves 2x2, 4x4 mfma; BN=64: 4 waves stacked on M,
// 2x4 mfma). XOR-swizzled LDS (slot s of row r holds k-chunk s^((r>>1)&3))
// so ds_read_b128 is <=2-way bank aliased (free).
// EPI: 0 = bias->bf16 ; 1 = bias+relu->bf16 ; 2 = bias+res->f32 + col stats
// ---------------------------------------------------------------------------
template<int BN, int EPI>
__global__ __launch_bounds__(256) void gemm_bf16(
    const unsigned short* __restrict__ Xb, const unsigned short* __restrict__ Wt,
    const float* __restrict__ bias, const float* __restrict__ res,
    float* __restrict__ outf, unsigned short* __restrict__ outb,
    float* __restrict__ sum, float* __restrict__ sumsq,
    int K, int Nc)
{
    constexpr int WM = (BN == 128) ? 4 : 2;   // mfma tiles per wave in M
    __shared__ __align__(16) unsigned short As[128 * 32];
    __shared__ __align__(16) unsigned short Bs[BN * 32];

    const int tid = threadIdx.x;
    const int lane = tid & 63;
    const int wv = tid >> 6;
    const int wm = (BN == 128) ? (wv >> 1) : wv;
    const int wn = (BN == 128) ? (wv & 1) : 0;
    const int m0 = blockIdx.y * 128, n0 = blockIdx.x * BN;
    const int lc = lane & 15, lq = lane >> 4;

    const int rowA = tid >> 2;                 // 0..63 (pass 2 adds 64)
    const int kof = ((tid & 3) ^ ((tid >> 3) & 3)) * 8;   // swizzled k-chunk
    unsigned short* ldsA = As + tid * 8;
    unsigned short* ldsB = Bs + tid * 8;

    const int rslot = (lq ^ ((lc >> 1) & 3)) * 8;   // read-side swizzled slot

    f32x4 acc[WM][4] = {};

    for (int k0 = 0; k0 < K; k0 += 32) {
        const unsigned short* gA = Xb + (size_t)(m0 + rowA) * K + k0 + kof;
        const unsigned short* gB = Wt + (size_t)(n0 + rowA) * K + k0 + kof;
        gld_lds16(gA, ldsA);
        gld_lds16(gA + (size_t)64 * K, ldsA + 2048);
        gld_lds16(gB, ldsB);
        if (BN == 128) gld_lds16(gB + (size_t)64 * K, ldsB + 2048);
        __syncthreads();

        bf16x8 af[WM], bfr[4];
        #pragma unroll
        for (int i = 0; i < WM; ++i)
            af[i] = *(const bf16x8*)&As[(wm * (WM * 16) + i * 16 + lc) * 32 + rslot];
        #pragma unroll
        for (int j = 0; j < 4; ++j)
            bfr[j] = *(const bf16x8*)&Bs[(wn * 64 + j * 16 + lc) * 32 + rslot];
        #pragma unroll
        for (int i = 0; i < WM; ++i)
            #pragma unroll
            for (int j = 0; j < 4; ++j)
                acc[i][j] = __builtin_amdgcn_mfma_f32_16x16x32_bf16(af[i], bfr[j], acc[i][j], 0, 0, 0);
        __syncthreads();
    }

    float cs[4] = {}, css[4] = {};
    #pragma unroll
    for (int i = 0; i < WM; ++i) {
        #pragma unroll
        for (int j = 0; j < 4; ++j) {
            const int gr0 = m0 + wm * (WM * 16) + i * 16 + lq * 4;
            const int gc = n0 + wn * 64 + j * 16 + lc;
            const float bi = bias[gc];
            #pragma unroll
            for (int r = 0; r < 4; ++r) {
                float val = acc[i][j][r] + bi;
                size_t off = (size_t)(gr0 + r) * Nc + gc;
                if (EPI == 0)      outb[off] = f2bf(val);
                else if (EPI == 1) outb[off] = f2bf(fmaxf(val, 0.f));
                else {
                    val += res[off];
                    outf[off] = val;
                    cs[j] += val; css[j] += val * val;
                }
            }
        }
    }
    if (EPI == 2) {
        // reduce across the 4 lq groups sharing each column, then 1 atomic/lane
        #pragma unroll
        for (int j = 0; j < 4; ++j) {
            float s = cs[j], ss = css[j];
            s += __shfl_xor(s, 16); s += __shfl_xor(s, 32);
            ss += __shfl_xor(ss, 16); ss += __shfl_xor(ss, 32);
            if (lq == 0) {
                const int gc = n0 + wn * 64 + j * 16 + lc;
                atomicAdd(&sum[gc], s);
                atomicAdd(&sumsq[gc], ss);
            }
        }
    }
}

// ---------------------------------------------------------------------------
// Prep kernels
// ---------------------------------------------------------------------------
__global__ __launch_bounds__(256) void conv_bf16v(
    const float4* __restrict__ in, unsigned int* __restrict__ out, int n4)
{
    int i = blockIdx.x * 256 + threadIdx.x;
    if (i < n4) {
        float4 f = in[i];
        out[i * 2]     = (unsigned int)f2bf(f.x) | ((unsigned int)f2bf(f.y) << 16);
        out[i * 2 + 1] = (unsigned int)f2bf(f.z) | ((unsigned int)f2bf(f.w) << 16);
    }
}

// all 6 weight transposes in one launch; blockIdx.z selects the matrix
__global__ __launch_bounds__(256) void transpose_all(
    const float* __restrict__ Wq, const float* __restrict__ Wk,
    const float* __restrict__ Wv, const float* __restrict__ Wo,
    const float* __restrict__ W1, const float* __restrict__ W2,
    unsigned short* __restrict__ wqkvT, unsigned short* __restrict__ woT,
    unsigned short* __restrict__ w1T, unsigned short* __restrict__ w2T)
{
    const float* in; unsigned short* out; int R, C;
    switch (blockIdx.z) {
        case 0: in = Wq; out = wqkvT;          R = 512;  C = 512;  break;
        case 1: in = Wk; out = wqkvT + 262144; R = 512;  C = 512;  break;
        case 2: in = Wv; out = wqkvT + 524288; R = 512;  C = 512;  break;
        case 3: in = Wo; out = woT;            R = 512;  C = 512;  break;
        case 4: in = W1; out = w1T;            R = 512;  C = 1024; break;
        default: in = W2; out = w2T;           R = 1024; C = 512;  break;
    }
    const int bc = blockIdx.x * 32, br = blockIdx.y * 32;
    if (bc >= C || br >= R) return;
    __shared__ float tile[32][33];
    const int tx = threadIdx.x & 31, ty = threadIdx.x >> 5;
    #pragma unroll
    for (int r = ty; r < 32; r += 8)
        tile[r][tx] = in[(size_t)(br + r) * C + bc + tx];
    __syncthreads();
    #pragma unroll
    for (int r = ty; r < 32; r += 8)
        out[(size_t)(bc + r) * R + br + tx] = f2bf(tile[tx][r]);
}

__global__ __launch_bounds__(256) void concat_bias(
    const float* __restrict__ bq, const float* __restrict__ bk,
    const float* __restrict__ bv, float* __restrict__ out)
{
    int i = blockIdx.x * 256 + threadIdx.x;
    out[i] = i < 512 ? bq[i] : (i < 1024 ? bk[i - 512] : bv[i - 1024]);
}

// ---------------------------------------------------------------------------
// Adjacency compaction: one wave per row, ballot-based ordered compaction.
// ---------------------------------------------------------------------------
__global__ __launch_bounds__(256) void build_adj(
    const float* __restrict__ A, int* __restrict__ idx, int* __restrict__ deg)
{
    int wave = (blockIdx.x * 256 + threadIdx.x) >> 6;
    int lane = threadIdx.x & 63;
    if (wave >= N_NODES) return;
    const float* row = A + (size_t)wave * N_NODES;
    int base = 0;
    for (int c0 = 0; c0 < N_NODES; c0 += 64) {
        float v = row[c0 + lane];
        unsigned long long m = __ballot(v > 0.0f);
        int before = __popcll(m & ((1ull << lane) - 1ull));
        if (v > 0.0f) {
            int p = base + before;
            if (p < MAXD) idx[wave * MAXD + p] = c0 + lane;
        }
        base += __popcll(m);
    }
    if (lane == 0) deg[wave] = base < MAXD ? base : MAXD;
}

// ---------------------------------------------------------------------------
// Sparse attention v3: block = node, 512 threads = 8 waves = 8 heads.
// Stage K and V rows of up to STAGE neighbors into LDS via global_load_lds
// (one 1KB row = one wave-wide 16B/lane DMA), then score/softmax/accum from
// LDS. Global fallback for d > STAGE (not hit at ~deg 34).
// ---------------------------------------------------------------------------
__global__ __launch_bounds__(512) void sparse_attn3(
    const unsigned short* __restrict__ qkv, const int* __restrict__ idx,
    const int* __restrict__ deg, unsigned short* __restrict__ o)
{
    __shared__ __align__(16) unsigned short ldsK[STAGE * 512];  // 64 KB
    __shared__ __align__(16) unsigned short ldsV[STAGE * 512];  // 64 KB
    __shared__ int s_idx[MAXD];
    __shared__ float s_p[8][MAXD];

    const int n = blockIdx.x;
    const int tid = threadIdx.x;
    const int h = tid >> 6;          // wave = head
    const int lane = tid & 63;

    const int d = deg[n];
    const int ds = d < STAGE ? d : STAGE;
    if (tid < d) s_idx[tid] = idx[n * MAXD + tid];
    __syncthreads();

    // bulk DMA: wave h stages neighbors h, h+8, h+16, ...
    for (int j = h; j < ds; j += 8) {
        const int m = s_idx[j];
        gld_lds16(qkv + (size_t)m * 1536 + 512 + lane * 8, ldsK + j * 512 + lane * 8);
        gld_lds16(qkv + (size_t)m * 1536 + 1024 + lane * 8, ldsV + j * 512 + lane * 8);
    }
    __syncthreads();   // drains vmcnt -> DMA complete

    const unsigned int* q32 = (const unsigned int*)qkv;
    const int jl = lane >> 4;        // neighbor sub-index (score)
    const int dg = lane & 15;        // dim group of 4
    const int half = lane >> 5, l2 = lane & 31;

    // q fragment
    uint2 qw = *(const uint2*)(q32 + n * 768 + h * 32 + dg * 2);
    const float q0 = bf2f(qw.x & 0xffff), q1 = bf2f(qw.x >> 16);
    const float q2 = bf2f(qw.y & 0xffff), q3 = bf2f(qw.y >> 16);

    // scores: 4 neighbors/iter, 16 lanes x 4 dims each
    for (int j0 = 0; j0 < d; j0 += 4) {
        const int jj = j0 + jl;
        float s = 0.f;
        if (jj < d) {
            uint2 kw;
            if (jj < ds) kw = *(const uint2*)(ldsK + jj * 512 + h * 64 + dg * 4);
            else         kw = *(const uint2*)(q32 + (size_t)s_idx[jj] * 768 + 256 + h * 32 + dg * 2);
            s = q0 * bf2f(kw.x & 0xffff) + q1 * bf2f(kw.x >> 16)
              + q2 * bf2f(kw.y & 0xffff) + q3 * bf2f(kw.y >> 16);
        }
        s += __shfl_xor(s, 1);
        s += __shfl_xor(s, 2);
        s += __shfl_xor(s, 4);
        s += __shfl_xor(s, 8);
        if (dg == 0 && jj < d) s_p[h][jj] = s * 0.125f;   // 1/sqrt(64)
    }

    // softmax
    float mx = -1e30f;
    for (int j = lane; j < d; j += 64) mx = fmaxf(mx, s_p[h][j]);
    #pragma unroll
    for (int off = 32; off; off >>= 1) mx = fmaxf(mx, __shfl_xor(mx, off));
    float sum = 0.f;
    for (int j = lane; j < d; j += 64) {
        float e = __expf(s_p[h][j] - mx);
        s_p[h][j] = e;
        sum += e;
    }
    #pragma unroll
    for (int off = 32; off; off >>= 1) sum += __shfl_xor(sum, off);
    const float inv = 1.0f / sum;

    // accumulate o: 32 lanes x 2 dims, 4 neighbors in flight
    float ax = 0.f, ay = 0.f;
    for (int j0 = 0; j0 < d; j0 += 8) {
        #pragma unroll
        for (int u = 0; u < 4; ++u) {
            const int jx = j0 + u * 2 + half;
            if (jx < d) {
                unsigned int vw;
                if (jx < ds) vw = *(const unsigned int*)(ldsV + jx * 512 + h * 64 + l2 * 2);
                else         vw = q32[(size_t)s_idx[jx] * 768 + 512 + h * 32 + l2];
                const float p = s_p[h][jx];
                ax += p * bf2f(vw & 0xffff);
                ay += p * bf2f(vw >> 16);
            }
        }
    }
    ax += __shfl_xor(ax, 32);
    ay += __shfl_xor(ay, 32);
    if (half == 0) {
        unsigned int pack = (unsigned int)f2bf(ax * inv)
                          | ((unsigned int)f2bf(ay * inv) << 16);
        ((unsigned int*)o)[n * 256 + h * 32 + l2] = pack;
    }
}

// ---------------------------------------------------------------------------
// BatchNorm apply (stats come fused from the preceding GEMM epilogue)
// ---------------------------------------------------------------------------
__global__ __launch_bounds__(256) void bn_apply(
    const float* __restrict__ x, const float* __restrict__ sum,
    const float* __restrict__ sumsq, const float* __restrict__ g,
    const float* __restrict__ b, float* __restrict__ yf,
    unsigned short* __restrict__ yb)
{
    const int i = blockIdx.x * 256 + threadIdx.x;
    const int c = i & (HID - 1);
    const float m = sum[c] * (1.0f / N_NODES);
    const float var = sumsq[c] * (1.0f / N_NODES) - m * m;
    const float inv = rsqrtf(var + EPS);
    const float val = g[c] * (x[i] - m) * inv + b[c];
    yf[i] = val;
    if (yb) yb[i] = f2bf(val);
}

// ---------------------------------------------------------------------------

extern "C" void kernel_launch(void* const* d_in, const int* in_sizes, int n_in,
                              void* d_out, int out_size, void* d_ws, size_t ws_size,
                              hipStream_t stream)
{
    const float* A   = (const float*)d_in[0];
    const float* h   = (const float*)d_in[1];
    const float* Wq  = (const float*)d_in[2];
    const float* bq  = (const float*)d_in[3];
    const float* Wk  = (const float*)d_in[4];
    const float* bk  = (const float*)d_in[5];
    const float* Wv  = (const float*)d_in[6];
    const float* bv  = (const float*)d_in[7];
    const float* Wo  = (const float*)d_in[8];
    const float* bo  = (const float*)d_in[9];
    const float* g1  = (const float*)d_in[10];
    const float* b1g = (const float*)d_in[11];
    const float* g2  = (const float*)d_in[12];
    const float* b2g = (const float*)d_in[13];
    const float* W1  = (const float*)d_in[14];
    const float* b1  = (const float*)d_in[15];
    const float* W2  = (const float*)d_in[16];
    const float* b2  = (const float*)d_in[17];
    float* out = (float*)d_out;

    float* ws = (float*)d_ws;
    unsigned short* hb    = (unsigned short*)(ws);               // 4096x512 bf16
    unsigned short* qkvb  = (unsigned short*)(ws + 1048576);     // 4096x1536 bf16
    unsigned short* o_bf  = (unsigned short*)(ws + 4194304);     // 4096x512 bf16
    unsigned short* wqkvT = (unsigned short*)(ws + 5242880);     // 1536x512 bf16
    unsigned short* woT   = (unsigned short*)(ws + 5636096);     // 512x512 bf16
    unsigned short* w1T   = (unsigned short*)(ws + 5767168);     // 1024x512 bf16
    unsigned short* w2T   = (unsigned short*)(ws + 6029312);     // 512x1024 bf16
    unsigned short* t_b   = (unsigned short*)(ws + 6291456);     // 4096x1024 bf16
    float* x1   = ws + 8388608;                                   // 4096x512 f32
    float* x2   = ws + 10485760;                                  // 4096x512 f32
    unsigned short* xb1_b = (unsigned short*)(ws + 12582912);    // 4096x512 bf16
    float* bqkv = ws + 13631488;                                  // 1536
    float* st   = ws + 13633024;                                  // 2048
    int*   adj  = (int*)(ws + 13635072);                          // 4096x128
    int*   deg  = adj + N_NODES * MAXD;

    // --- prep ---
    hipMemsetAsync(st, 0, 2048 * sizeof(float), stream);
    conv_bf16v<<<dim3(2048), dim3(256), 0, stream>>>(
        (const float4*)h, (unsigned int*)hb, N_NODES * HID / 4);
    transpose_all<<<dim3(32, 32, 6), dim3(256), 0, stream>>>(
        Wq, Wk, Wv, Wo, W1, W2, wqkvT, woT, w1T, w2T);
    concat_bias<<<dim3(6), dim3(256), 0, stream>>>(bq, bk, bv, bqkv);
    build_adj<<<dim3(N_NODES / 4), dim3(256), 0, stream>>>(A, adj, deg);

    // --- fused QKV projection ---
    gemm_bf16<128, 0><<<dim3(12, 32), dim3(256), 0, stream>>>(
        hb, wqkvT, bqkv, nullptr, nullptr, qkvb, nullptr, nullptr, 512, 1536);

    // --- sparse masked attention (LDS-staged) ---
    sparse_attn3<<<dim3(N_NODES), dim3(512), 0, stream>>>(qkvb, adj, deg, o_bf);

    // --- O projection + residual + fused BN1 stats ---
    gemm_bf16<64, 2><<<dim3(8, 32), dim3(256), 0, stream>>>(
        o_bf, woT, bo, h, x1, nullptr, st, st + 512, 512, 512);

    // --- BN1 apply ---
    bn_apply<<<dim3(8192), dim3(256), 0, stream>>>(x1, st, st + 512, g1, b1g, x1, xb1_b);

    // --- FFN ---
    gemm_bf16<128, 1><<<dim3(8, 32), dim3(256), 0, stream>>>(
        xb1_b, w1T, b1, nullptr, nullptr, t_b, nullptr, nullptr, 512, 1024);
    gemm_bf16<64, 2><<<dim3(8, 32), dim3(256), 0, stream>>>(
        t_b, w2T, b2, x1, x2, nullptr, st + 1024, st + 1536, 1024, 512);

    // --- BN2 apply -> out ---
    bn_apply<<<dim3(8192), dim3(256), 0, stream>>>(
        x2, st + 1024, st + 1536, g2, b2g, out, nullptr);

    (void)in_sizes; (void)n_in; (void)out_size; (void)ws_size;
}

// Round 4
// 258.694 us; speedup vs baseline: 2.3222x; 1.4212x over previous
//
#include <hip/hip_runtime.h>

#define N_NODES 4096
#define HID 512
#define HEADS 8
#define DH 64
#define EPS 1e-5f
#define MAXD 128

typedef __attribute__((ext_vector_type(8))) short bf16x8;
typedef __attribute__((ext_vector_type(4))) float f32x4;

__device__ __forceinline__ unsigned short f2bf(float f) {
    unsigned int u = __float_as_uint(f);
    unsigned int r = (u + 0x7FFFu + ((u >> 16) & 1u)) >> 16;   // RNE
    return (unsigned short)r;
}
__device__ __forceinline__ float blo(unsigned int u) {        // low bf16 -> f32
    return __uint_as_float(u << 16);
}
__device__ __forceinline__ float bhi(unsigned int u) {        // high bf16 -> f32
    return __uint_as_float(u & 0xffff0000u);
}

__device__ __forceinline__ void gld_lds16(const void* g, void* l) {
    __builtin_amdgcn_global_load_lds(
        (const __attribute__((address_space(1))) unsigned int*)g,
        (__attribute__((address_space(3))) unsigned int*)l, 16, 0, 0);
}

// ---------------------------------------------------------------------------
// bf16 MFMA GEMM: C[M x Nc] = X[M x K] @ W^T  (Wt[Nc][K] K-major)
// 128xBN tile (BN=128: 4 waves 2x2, 4x4 mfma; BN=64: 4 waves stacked on M,
// 2x4 mfma). XOR-swizzled LDS so ds_read_b128 is <=2-way bank aliased (free).
// EPI: 0 = bias->bf16 ; 1 = bias+relu->bf16 ; 2 = bias+res->f32 + col stats
// ---------------------------------------------------------------------------
template<int BN, int EPI>
__global__ __launch_bounds__(256) void gemm_bf16(
    const unsigned short* __restrict__ Xb, const unsigned short* __restrict__ Wt,
    const float* __restrict__ bias, const float* __restrict__ res,
    float* __restrict__ outf, unsigned short* __restrict__ outb,
    float* __restrict__ sum, float* __restrict__ sumsq,
    int K, int Nc)
{
    constexpr int WM = (BN == 128) ? 4 : 2;   // mfma tiles per wave in M
    __shared__ __align__(16) unsigned short As[128 * 32];
    __shared__ __align__(16) unsigned short Bs[BN * 32];

    const int tid = threadIdx.x;
    const int lane = tid & 63;
    const int wv = tid >> 6;
    const int wm = (BN == 128) ? (wv >> 1) : wv;
    const int wn = (BN == 128) ? (wv & 1) : 0;
    const int m0 = blockIdx.y * 128, n0 = blockIdx.x * BN;
    const int lc = lane & 15, lq = lane >> 4;

    const int rowA = tid >> 2;                 // 0..63 (pass 2 adds 64)
    const int kof = ((tid & 3) ^ ((tid >> 3) & 3)) * 8;   // swizzled k-chunk
    unsigned short* ldsA = As + tid * 8;
    unsigned short* ldsB = Bs + tid * 8;

    const int rslot = (lq ^ ((lc >> 1) & 3)) * 8;   // read-side swizzled slot

    f32x4 acc[WM][4] = {};

    for (int k0 = 0; k0 < K; k0 += 32) {
        const unsigned short* gA = Xb + (size_t)(m0 + rowA) * K + k0 + kof;
        const unsigned short* gB = Wt + (size_t)(n0 + rowA) * K + k0 + kof;
        gld_lds16(gA, ldsA);
        gld_lds16(gA + (size_t)64 * K, ldsA + 2048);
        gld_lds16(gB, ldsB);
        if (BN == 128) gld_lds16(gB + (size_t)64 * K, ldsB + 2048);
        __syncthreads();

        bf16x8 af[WM], bfr[4];
        #pragma unroll
        for (int i = 0; i < WM; ++i)
            af[i] = *(const bf16x8*)&As[(wm * (WM * 16) + i * 16 + lc) * 32 + rslot];
        #pragma unroll
        for (int j = 0; j < 4; ++j)
            bfr[j] = *(const bf16x8*)&Bs[(wn * 64 + j * 16 + lc) * 32 + rslot];
        #pragma unroll
        for (int i = 0; i < WM; ++i)
            #pragma unroll
            for (int j = 0; j < 4; ++j)
                acc[i][j] = __builtin_amdgcn_mfma_f32_16x16x32_bf16(af[i], bfr[j], acc[i][j], 0, 0, 0);
        __syncthreads();
    }

    float cs[4] = {}, css[4] = {};
    #pragma unroll
    for (int i = 0; i < WM; ++i) {
        #pragma unroll
        for (int j = 0; j < 4; ++j) {
            const int gr0 = m0 + wm * (WM * 16) + i * 16 + lq * 4;
            const int gc = n0 + wn * 64 + j * 16 + lc;
            const float bi = bias[gc];
            #pragma unroll
            for (int r = 0; r < 4; ++r) {
                float val = acc[i][j][r] + bi;
                size_t off = (size_t)(gr0 + r) * Nc + gc;
                if (EPI == 0)      outb[off] = f2bf(val);
                else if (EPI == 1) outb[off] = f2bf(fmaxf(val, 0.f));
                else {
                    val += res[off];
                    outf[off] = val;
                    cs[j] += val; css[j] += val * val;
                }
            }
        }
    }
    if (EPI == 2) {
        #pragma unroll
        for (int j = 0; j < 4; ++j) {
            float s = cs[j], ss = css[j];
            s += __shfl_xor(s, 16); s += __shfl_xor(s, 32);
            ss += __shfl_xor(ss, 16); ss += __shfl_xor(ss, 32);
            if (lq == 0) {
                const int gc = n0 + wn * 64 + j * 16 + lc;
                atomicAdd(&sum[gc], s);
                atomicAdd(&sumsq[gc], ss);
            }
        }
    }
}

// ---------------------------------------------------------------------------
// Prep kernels
// ---------------------------------------------------------------------------
__global__ __launch_bounds__(256) void conv_bf16v(
    const float4* __restrict__ in, unsigned int* __restrict__ out, int n4)
{
    int i = blockIdx.x * 256 + threadIdx.x;
    if (i < n4) {
        float4 f = in[i];
        out[i * 2]     = (unsigned int)f2bf(f.x) | ((unsigned int)f2bf(f.y) << 16);
        out[i * 2 + 1] = (unsigned int)f2bf(f.z) | ((unsigned int)f2bf(f.w) << 16);
    }
}

__global__ __launch_bounds__(256) void transpose_all(
    const float* __restrict__ Wq, const float* __restrict__ Wk,
    const float* __restrict__ Wv, const float* __restrict__ Wo,
    const float* __restrict__ W1, const float* __restrict__ W2,
    unsigned short* __restrict__ wqkvT, unsigned short* __restrict__ woT,
    unsigned short* __restrict__ w1T, unsigned short* __restrict__ w2T)
{
    const float* in; unsigned short* out; int R, C;
    switch (blockIdx.z) {
        case 0: in = Wq; out = wqkvT;          R = 512;  C = 512;  break;
        case 1: in = Wk; out = wqkvT + 262144; R = 512;  C = 512;  break;
        case 2: in = Wv; out = wqkvT + 524288; R = 512;  C = 512;  break;
        case 3: in = Wo; out = woT;            R = 512;  C = 512;  break;
        case 4: in = W1; out = w1T;            R = 512;  C = 1024; break;
        default: in = W2; out = w2T;           R = 1024; C = 512;  break;
    }
    const int bc = blockIdx.x * 32, br = blockIdx.y * 32;
    if (bc >= C || br >= R) return;
    __shared__ float tile[32][33];
    const int tx = threadIdx.x & 31, ty = threadIdx.x >> 5;
    #pragma unroll
    for (int r = ty; r < 32; r += 8)
        tile[r][tx] = in[(size_t)(br + r) * C + bc + tx];
    __syncthreads();
    #pragma unroll
    for (int r = ty; r < 32; r += 8)
        out[(size_t)(bc + r) * R + br + tx] = f2bf(tile[tx][r]);
}

__global__ __launch_bounds__(256) void concat_bias(
    const float* __restrict__ bq, const float* __restrict__ bk,
    const float* __restrict__ bv, float* __restrict__ out)
{
    int i = blockIdx.x * 256 + threadIdx.x;
    out[i] = i < 512 ? bq[i] : (i < 1024 ? bk[i - 512] : bv[i - 1024]);
}

// ---------------------------------------------------------------------------
// Adjacency compaction, float4 loads: wave per row, 16 outer iterations.
// Order within each 256-col chunk is bit-plane order (irrelevant for softmax).
// ---------------------------------------------------------------------------
__global__ __launch_bounds__(256) void build_adj(
    const float* __restrict__ A, int* __restrict__ idx, int* __restrict__ deg)
{
    int row = (blockIdx.x * 256 + threadIdx.x) >> 6;
    int lane = threadIdx.x & 63;
    if (row >= N_NODES) return;
    const float4* r4 = (const float4*)(A + (size_t)row * N_NODES);
    int base = 0;
    for (int c0 = 0; c0 < N_NODES; c0 += 256) {
        float4 v = r4[(c0 >> 2) + lane];
        #pragma unroll
        for (int b = 0; b < 4; ++b) {
            float vb = (b == 0) ? v.x : (b == 1) ? v.y : (b == 2) ? v.z : v.w;
            unsigned long long m = __ballot(vb > 0.0f);
            int before = __popcll(m & ((1ull << lane) - 1ull));
            if (vb > 0.0f) {
                int p = base + before;
                if (p < MAXD) idx[row * MAXD + p] = c0 + lane * 4 + b;
            }
            base += __popcll(m);
        }
    }
    if (lane == 0) deg[row] = base < MAXD ? base : MAXD;
}

// ---------------------------------------------------------------------------
// Sparse attention v4: block = node (256 thr, 4 waves); wave wv processes
// heads wv and wv+4 IN THE SAME LOOPS (2 loads per addr calc, 512B apart).
// Score: 8 neighbors/iter (8 lanes x 8 dims, uint4, 3-shuffle reduce).
// Accum: 4 neighbors/iter (16 lanes x 4 dims, uint2, end-reduce).
// 1-deep software prefetch on both gather loops. No big LDS -> 28-80 VGPR,
// high occupancy (the v3 LDS-staging experiment crashed occupancy to 1
// block/CU and regressed 2x; do NOT re-stage K/V in LDS here).
// ---------------------------------------------------------------------------
__global__ __launch_bounds__(256) void sparse_attn4(
    const unsigned short* __restrict__ qkv, const int* __restrict__ idx,
    const int* __restrict__ deg, unsigned short* __restrict__ o)
{
    const int n = blockIdx.x;
    const int tid = threadIdx.x;
    const int wv = tid >> 6, lane = tid & 63;

    __shared__ int s_idx[MAXD];
    __shared__ float s_p[8][MAXD];

    const int d = deg[n];
    for (int i = tid; i < d; i += 256) s_idx[i] = idx[n * MAXD + i];
    __syncthreads();

    const int jl = lane >> 3;      // neighbor sub-index (score), 0..7
    const int dgs = lane & 7;      // dim-group of 8 (score)
    const int jl2 = lane >> 4;     // neighbor sub-index (accum), 0..3
    const int dga = lane & 15;     // dim-group of 4 (accum)

    const int h0 = wv, h1 = wv + 4;

    // q fragments for both heads: dims dgs*8 .. +7
    const unsigned short* qp = qkv + (size_t)n * 1536 + dgs * 8;
    uint4 qa = *(const uint4*)(qp + h0 * 64);
    uint4 qb = *(const uint4*)(qp + h1 * 64);
    const float a0 = blo(qa.x), a1 = bhi(qa.x), a2 = blo(qa.y), a3 = bhi(qa.y);
    const float a4 = blo(qa.z), a5 = bhi(qa.z), a6 = blo(qa.w), a7 = bhi(qa.w);
    const float b0 = blo(qb.x), b1 = bhi(qb.x), b2 = blo(qb.y), b3 = bhi(qb.y);
    const float b4 = blo(qb.z), b5 = bhi(qb.z), b6 = blo(qb.w), b7 = bhi(qb.w);

    // ---- scores, both heads, prefetched ----
    uint4 ka = {0, 0, 0, 0}, kb = {0, 0, 0, 0};
    if (jl < d) {
        const unsigned short* p = qkv + (size_t)s_idx[jl] * 1536 + 512 + dgs * 8;
        ka = *(const uint4*)(p + h0 * 64);
        kb = *(const uint4*)(p + h1 * 64);
    }
    for (int j0 = 0; j0 < d; j0 += 8) {
        const uint4 ca = ka, cb = kb;
        const int jn = j0 + 8 + jl;
        if (jn < d) {
            const unsigned short* p = qkv + (size_t)s_idx[jn] * 1536 + 512 + dgs * 8;
            ka = *(const uint4*)(p + h0 * 64);
            kb = *(const uint4*)(p + h1 * 64);
        }
        const int jc = j0 + jl;
        float s0 = 0.f, s1 = 0.f;
        if (jc < d) {
            s0 = a0 * blo(ca.x) + a1 * bhi(ca.x) + a2 * blo(ca.y) + a3 * bhi(ca.y)
               + a4 * blo(ca.z) + a5 * bhi(ca.z) + a6 * blo(ca.w) + a7 * bhi(ca.w);
            s1 = b0 * blo(cb.x) + b1 * bhi(cb.x) + b2 * blo(cb.y) + b3 * bhi(cb.y)
               + b4 * blo(cb.z) + b5 * bhi(cb.z) + b6 * blo(cb.w) + b7 * bhi(cb.w);
        }
        s0 += __shfl_xor(s0, 1); s1 += __shfl_xor(s1, 1);
        s0 += __shfl_xor(s0, 2); s1 += __shfl_xor(s1, 2);
        s0 += __shfl_xor(s0, 4); s1 += __shfl_xor(s1, 4);
        if (dgs == 0 && jc < d) {
            s_p[h0][jc] = s0 * 0.125f;    // 1/sqrt(64)
            s_p[h1][jc] = s1 * 0.125f;
        }
    }

    // ---- softmax per head ----
    float inv0, inv1;
    #pragma unroll
    for (int hh = 0; hh < 2; ++hh) {
        float* sp = s_p[hh ? h1 : h0];
        float mx = -1e30f;
        for (int j = lane; j < d; j += 64) mx = fmaxf(mx, sp[j]);
        #pragma unroll
        for (int off = 32; off; off >>= 1) mx = fmaxf(mx, __shfl_xor(mx, off));
        float sum = 0.f;
        for (int j = lane; j < d; j += 64) {
            float e = __expf(sp[j] - mx);
            sp[j] = e;
            sum += e;
        }
        #pragma unroll
        for (int off = 32; off; off >>= 1) sum += __shfl_xor(sum, off);
        if (hh) inv1 = 1.0f / sum; else inv0 = 1.0f / sum;
    }

    // ---- accumulate o, both heads, prefetched ----
    float x0 = 0.f, x1 = 0.f, x2 = 0.f, x3 = 0.f;   // head h0, dims dga*4..+3
    float y0 = 0.f, y1 = 0.f, y2 = 0.f, y3 = 0.f;   // head h1
    uint2 va = {0, 0}, vb = {0, 0};
    if (jl2 < d) {
        const unsigned short* p = qkv + (size_t)s_idx[jl2] * 1536 + 1024 + dga * 4;
        va = *(const uint2*)(p + h0 * 64);
        vb = *(const uint2*)(p + h1 * 64);
    }
    for (int j0 = 0; j0 < d; j0 += 4) {
        const uint2 ca = va, cb = vb;
        const int jn = j0 + 4 + jl2;
        if (jn < d) {
            const unsigned short* p = qkv + (size_t)s_idx[jn] * 1536 + 1024 + dga * 4;
            va = *(const uint2*)(p + h0 * 64);
            vb = *(const uint2*)(p + h1 * 64);
        }
        const int jc = j0 + jl2;
        if (jc < d) {
            const float p0 = s_p[h0][jc], p1 = s_p[h1][jc];
            x0 += p0 * blo(ca.x); x1 += p0 * bhi(ca.x);
            x2 += p0 * blo(ca.y); x3 += p0 * bhi(ca.y);
            y0 += p1 * blo(cb.x); y1 += p1 * bhi(cb.x);
            y2 += p1 * blo(cb.y); y3 += p1 * bhi(cb.y);
        }
    }
    x0 += __shfl_xor(x0, 16); x0 += __shfl_xor(x0, 32);
    x1 += __shfl_xor(x1, 16); x1 += __shfl_xor(x1, 32);
    x2 += __shfl_xor(x2, 16); x2 += __shfl_xor(x2, 32);
    x3 += __shfl_xor(x3, 16); x3 += __shfl_xor(x3, 32);
    y0 += __shfl_xor(y0, 16); y0 += __shfl_xor(y0, 32);
    y1 += __shfl_xor(y1, 16); y1 += __shfl_xor(y1, 32);
    y2 += __shfl_xor(y2, 16); y2 += __shfl_xor(y2, 32);
    y3 += __shfl_xor(y3, 16); y3 += __shfl_xor(y3, 32);
    if (jl2 == 0) {
        uint2 w0, w1;
        w0.x = (unsigned int)f2bf(x0 * inv0) | ((unsigned int)f2bf(x1 * inv0) << 16);
        w0.y = (unsigned int)f2bf(x2 * inv0) | ((unsigned int)f2bf(x3 * inv0) << 16);
        w1.x = (unsigned int)f2bf(y0 * inv1) | ((unsigned int)f2bf(y1 * inv1) << 16);
        w1.y = (unsigned int)f2bf(y2 * inv1) | ((unsigned int)f2bf(y3 * inv1) << 16);
        *(uint2*)(o + (size_t)n * 512 + h0 * 64 + dga * 4) = w0;
        *(uint2*)(o + (size_t)n * 512 + h1 * 64 + dga * 4) = w1;
    }
}

// ---------------------------------------------------------------------------
// BatchNorm apply, float4 (stats come fused from the preceding GEMM epilogue)
// ---------------------------------------------------------------------------
__global__ __launch_bounds__(256) void bn_apply4(
    const float4* __restrict__ x, const float* __restrict__ sum,
    const float* __restrict__ sumsq, const float* __restrict__ g,
    const float* __restrict__ b, float4* __restrict__ yf,
    uint2* __restrict__ yb)
{
    const int i = blockIdx.x * 256 + threadIdx.x;   // float4 index over N*HID/4
    const int c4 = i & 127;                          // float4 column index
    const float4 s4 = ((const float4*)sum)[c4];
    const float4 q4 = ((const float4*)sumsq)[c4];
    const float4 g4 = ((const float4*)g)[c4];
    const float4 b4 = ((const float4*)b)[c4];
    const float4 xv = x[i];
    const float kN = 1.0f / N_NODES;
    float4 r;
    {
        float m = s4.x * kN; r.x = g4.x * (xv.x - m) * rsqrtf(q4.x * kN - m * m + EPS) + b4.x;
    }
    {
        float m = s4.y * kN; r.y = g4.y * (xv.y - m) * rsqrtf(q4.y * kN - m * m + EPS) + b4.y;
    }
    {
        float m = s4.z * kN; r.z = g4.z * (xv.z - m) * rsqrtf(q4.z * kN - m * m + EPS) + b4.z;
    }
    {
        float m = s4.w * kN; r.w = g4.w * (xv.w - m) * rsqrtf(q4.w * kN - m * m + EPS) + b4.w;
    }
    yf[i] = r;
    if (yb) {
        uint2 p;
        p.x = (unsigned int)f2bf(r.x) | ((unsigned int)f2bf(r.y) << 16);
        p.y = (unsigned int)f2bf(r.z) | ((unsigned int)f2bf(r.w) << 16);
        yb[i] = p;
    }
}

// ---------------------------------------------------------------------------

extern "C" void kernel_launch(void* const* d_in, const int* in_sizes, int n_in,
                              void* d_out, int out_size, void* d_ws, size_t ws_size,
                              hipStream_t stream)
{
    const float* A   = (const float*)d_in[0];
    const float* h   = (const float*)d_in[1];
    const float* Wq  = (const float*)d_in[2];
    const float* bq  = (const float*)d_in[3];
    const float* Wk  = (const float*)d_in[4];
    const float* bk  = (const float*)d_in[5];
    const float* Wv  = (const float*)d_in[6];
    const float* bv  = (const float*)d_in[7];
    const float* Wo  = (const float*)d_in[8];
    const float* bo  = (const float*)d_in[9];
    const float* g1  = (const float*)d_in[10];
    const float* b1g = (const float*)d_in[11];
    const float* g2  = (const float*)d_in[12];
    const float* b2g = (const float*)d_in[13];
    const float* W1  = (const float*)d_in[14];
    const float* b1  = (const float*)d_in[15];
    const float* W2  = (const float*)d_in[16];
    const float* b2  = (const float*)d_in[17];
    float* out = (float*)d_out;

    float* ws = (float*)d_ws;
    unsigned short* hb    = (unsigned short*)(ws);               // 4096x512 bf16
    unsigned short* qkvb  = (unsigned short*)(ws + 1048576);     // 4096x1536 bf16
    unsigned short* o_bf  = (unsigned short*)(ws + 4194304);     // 4096x512 bf16
    unsigned short* wqkvT = (unsigned short*)(ws + 5242880);     // 1536x512 bf16
    unsigned short* woT   = (unsigned short*)(ws + 5636096);     // 512x512 bf16
    unsigned short* w1T   = (unsigned short*)(ws + 5767168);     // 1024x512 bf16
    unsigned short* w2T   = (unsigned short*)(ws + 6029312);     // 512x1024 bf16
    unsigned short* t_b   = (unsigned short*)(ws + 6291456);     // 4096x1024 bf16
    float* x1   = ws + 8388608;                                   // 4096x512 f32
    float* x2   = ws + 10485760;                                  // 4096x512 f32
    unsigned short* xb1_b = (unsigned short*)(ws + 12582912);    // 4096x512 bf16
    float* bqkv = ws + 13631488;                                  // 1536
    float* st   = ws + 13633024;                                  // 2048
    int*   adj  = (int*)(ws + 13635072);                          // 4096x128
    int*   deg  = adj + N_NODES * MAXD;

    // --- prep ---
    hipMemsetAsync(st, 0, 2048 * sizeof(float), stream);
    conv_bf16v<<<dim3(2048), dim3(256), 0, stream>>>(
        (const float4*)h, (unsigned int*)hb, N_NODES * HID / 4);
    transpose_all<<<dim3(32, 32, 6), dim3(256), 0, stream>>>(
        Wq, Wk, Wv, Wo, W1, W2, wqkvT, woT, w1T, w2T);
    concat_bias<<<dim3(6), dim3(256), 0, stream>>>(bq, bk, bv, bqkv);
    build_adj<<<dim3(N_NODES / 4), dim3(256), 0, stream>>>(A, adj, deg);

    // --- fused QKV projection ---
    gemm_bf16<128, 0><<<dim3(12, 32), dim3(256), 0, stream>>>(
        hb, wqkvT, bqkv, nullptr, nullptr, qkvb, nullptr, nullptr, 512, 1536);

    // --- sparse masked attention ---
    sparse_attn4<<<dim3(N_NODES), dim3(256), 0, stream>>>(qkvb, adj, deg, o_bf);

    // --- O projection + residual + fused BN1 stats ---
    gemm_bf16<64, 2><<<dim3(8, 32), dim3(256), 0, stream>>>(
        o_bf, woT, bo, h, x1, nullptr, st, st + 512, 512, 512);

    // --- BN1 apply ---
    bn_apply4<<<dim3(2048), dim3(256), 0, stream>>>(
        (const float4*)x1, st, st + 512, g1, b1g, (float4*)x1, (uint2*)xb1_b);

    // --- FFN ---
    gemm_bf16<128, 1><<<dim3(8, 32), dim3(256), 0, stream>>>(
        xb1_b, w1T, b1, nullptr, nullptr, t_b, nullptr, nullptr, 512, 1024);
    gemm_bf16<64, 2><<<dim3(8, 32), dim3(256), 0, stream>>>(
        t_b, w2T, b2, x1, x2, nullptr, st + 1024, st + 1536, 1024, 512);

    // --- BN2 apply -> out ---
    bn_apply4<<<dim3(2048), dim3(256), 0, stream>>>(
        (const float4*)x2, st + 1024, st + 1536, g2, b2g, (float4*)out, nullptr);

    (void)in_sizes; (void)n_in; (void)out_size; (void)ws_size;
}

// Round 5
// 242.517 us; speedup vs baseline: 2.4771x; 1.0667x over previous
//
#include <hip/hip_runtime.h>

#define N_NODES 4096
#define HID 512
#define HEADS 8
#define DH 64
#define EPS 1e-5f
#define MAXD 128

typedef __attribute__((ext_vector_type(8))) short bf16x8;
typedef __attribute__((ext_vector_type(4))) float f32x4;

__device__ __forceinline__ unsigned short f2bf(float f) {
    unsigned int u = __float_as_uint(f);
    unsigned int r = (u + 0x7FFFu + ((u >> 16) & 1u)) >> 16;   // RNE
    return (unsigned short)r;
}
__device__ __forceinline__ float blo(unsigned int u) {        // low bf16 -> f32
    return __uint_as_float(u << 16);
}
__device__ __forceinline__ float bhi(unsigned int u) {        // high bf16 -> f32
    return __uint_as_float(u & 0xffff0000u);
}

__device__ __forceinline__ void gld_lds16(const void* g, void* l) {
    __builtin_amdgcn_global_load_lds(
        (const __attribute__((address_space(1))) unsigned int*)g,
        (__attribute__((address_space(3))) unsigned int*)l, 16, 0, 0);
}

// ---------------------------------------------------------------------------
// bf16 MFMA GEMM: C[M x Nc] = X[M x K] @ W^T  (Wt[Nc][K] K-major)
// 128xBN tile, BK=64 (halves barrier drains vs BK=32; LDS 32KB keeps ~3
// blocks/CU — do NOT go to BK=128, that's the 2-block occupancy cliff).
// Staging: instr p covers rows p*32+(tid>>3); lane fetches global k-chunk
// (tid&7)^(row&7) so LDS slot s of row r holds chunk s^(r&7). Read slot
// (h*4+lq)^(lc&7) -> each 4-bank group hit by exactly 8 lanes (b128 minimum,
// conflict-free).
// EPI: 0 = bias->bf16 ; 1 = bias+relu->bf16 ; 2 = bias+res->f32 + col stats
// ---------------------------------------------------------------------------
template<int BN, int EPI>
__global__ __launch_bounds__(256) void gemm_bf16(
    const unsigned short* __restrict__ Xb, const unsigned short* __restrict__ Wt,
    const float* __restrict__ bias, const float* __restrict__ res,
    float* __restrict__ outf, unsigned short* __restrict__ outb,
    float* __restrict__ sum, float* __restrict__ sumsq,
    int K, int Nc)
{
    constexpr int WM = (BN == 128) ? 4 : 2;   // mfma tiles per wave in M
    __shared__ __align__(16) unsigned short As[128 * 64];   // 16 KB
    __shared__ __align__(16) unsigned short Bs[BN * 64];    // 16/8 KB

    const int tid = threadIdx.x;
    const int lane = tid & 63;
    const int wv = tid >> 6;
    const int wm = (BN == 128) ? (wv >> 1) : wv;
    const int wn = (BN == 128) ? (wv & 1) : 0;
    const int m0 = blockIdx.y * 128, n0 = blockIdx.x * BN;
    const int lc = lane & 15, lq = lane >> 4;

    const int srow = tid >> 3;                       // 0..31
    const int schunk = (tid & 7) ^ (srow & 7);       // swizzled global k-chunk
    unsigned short* ldsA = As + tid * 8;             // DMA-forced contiguous
    unsigned short* ldsB = Bs + tid * 8;

    const int rs0 = lq ^ (lc & 7);                   // read slot, k-half 0
    const int rs1 = (4 + lq) ^ (lc & 7);             // read slot, k-half 1

    f32x4 acc[WM][4] = {};

    for (int k0 = 0; k0 < K; k0 += 64) {
        const unsigned short* gA = Xb + (size_t)(m0 + srow) * K + k0 + schunk * 8;
        const unsigned short* gB = Wt + (size_t)(n0 + srow) * K + k0 + schunk * 8;
        #pragma unroll
        for (int p = 0; p < 4; ++p)
            gld_lds16(gA + (size_t)(p * 32) * K, ldsA + p * 2048);
        #pragma unroll
        for (int p = 0; p < BN / 32; ++p)
            gld_lds16(gB + (size_t)(p * 32) * K, ldsB + p * 2048);
        __syncthreads();

        #pragma unroll
        for (int h = 0; h < 2; ++h) {
            const int rs = h ? rs1 : rs0;
            bf16x8 af[WM], bfr[4];
            #pragma unroll
            for (int i = 0; i < WM; ++i)
                af[i] = *(const bf16x8*)&As[(wm * (WM * 16) + i * 16 + lc) * 64 + rs * 8];
            #pragma unroll
            for (int j = 0; j < 4; ++j)
                bfr[j] = *(const bf16x8*)&Bs[(wn * 64 + j * 16 + lc) * 64 + rs * 8];
            #pragma unroll
            for (int i = 0; i < WM; ++i)
                #pragma unroll
                for (int j = 0; j < 4; ++j)
                    acc[i][j] = __builtin_amdgcn_mfma_f32_16x16x32_bf16(af[i], bfr[j], acc[i][j], 0, 0, 0);
        }
        __syncthreads();
    }

    float cs[4] = {}, css[4] = {};
    #pragma unroll
    for (int i = 0; i < WM; ++i) {
        #pragma unroll
        for (int j = 0; j < 4; ++j) {
            const int gr0 = m0 + wm * (WM * 16) + i * 16 + lq * 4;
            const int gc = n0 + wn * 64 + j * 16 + lc;
            const float bi = bias[gc];
            #pragma unroll
            for (int r = 0; r < 4; ++r) {
                float val = acc[i][j][r] + bi;
                size_t off = (size_t)(gr0 + r) * Nc + gc;
                if (EPI == 0)      outb[off] = f2bf(val);
                else if (EPI == 1) outb[off] = f2bf(fmaxf(val, 0.f));
                else {
                    val += res[off];
                    outf[off] = val;
                    cs[j] += val; css[j] += val * val;
                }
            }
        }
    }
    if (EPI == 2) {
        #pragma unroll
        for (int j = 0; j < 4; ++j) {
            float s = cs[j], ss = css[j];
            s += __shfl_xor(s, 16); s += __shfl_xor(s, 32);
            ss += __shfl_xor(ss, 16); ss += __shfl_xor(ss, 32);
            if (lq == 0) {
                const int gc = n0 + wn * 64 + j * 16 + lc;
                atomicAdd(&sum[gc], s);
                atomicAdd(&sumsq[gc], ss);
            }
        }
    }
}

// ---------------------------------------------------------------------------
// Fused prep: z=0..5 weight transposes, z=6 h->bf16, z=7 bias concat + zero
// ---------------------------------------------------------------------------
__global__ __launch_bounds__(256) void prep_all(
    const float* __restrict__ Wq, const float* __restrict__ Wk,
    const float* __restrict__ Wv, const float* __restrict__ Wo,
    const float* __restrict__ W1, const float* __restrict__ W2,
    const float* __restrict__ h,
    const float* __restrict__ bq, const float* __restrict__ bk,
    const float* __restrict__ bv,
    unsigned short* __restrict__ wqkvT, unsigned short* __restrict__ woT,
    unsigned short* __restrict__ w1T, unsigned short* __restrict__ w2T,
    unsigned int* __restrict__ hb, float* __restrict__ bqkv,
    float* __restrict__ st)
{
    const int z = blockIdx.z;
    if (z < 6) {
        const float* in; unsigned short* out; int R, C;
        switch (z) {
            case 0: in = Wq; out = wqkvT;          R = 512;  C = 512;  break;
            case 1: in = Wk; out = wqkvT + 262144; R = 512;  C = 512;  break;
            case 2: in = Wv; out = wqkvT + 524288; R = 512;  C = 512;  break;
            case 3: in = Wo; out = woT;            R = 512;  C = 512;  break;
            case 4: in = W1; out = w1T;            R = 512;  C = 1024; break;
            default: in = W2; out = w2T;           R = 1024; C = 512;  break;
        }
        const int bc = blockIdx.x * 32, br = blockIdx.y * 32;
        if (bc >= C || br >= R) return;
        __shared__ float tile[32][33];
        const int tx = threadIdx.x & 31, ty = threadIdx.x >> 5;
        #pragma unroll
        for (int r = ty; r < 32; r += 8)
            tile[r][tx] = in[(size_t)(br + r) * C + bc + tx];
        __syncthreads();
        #pragma unroll
        for (int r = ty; r < 32; r += 8)
            out[(size_t)(bc + r) * R + br + tx] = f2bf(tile[tx][r]);
    } else if (z == 6) {
        // h (4096x512 f32) -> bf16; 1024 blocks x 256 thr x 2 float4
        const int blk = blockIdx.y * 32 + blockIdx.x;
        const int i = blk * 512 + threadIdx.x * 2;   // float4 index (524288 total)
        const float4* in4 = (const float4*)h;
        #pragma unroll
        for (int u = 0; u < 2; ++u) {
            float4 f = in4[i + u];
            hb[(i + u) * 2]     = (unsigned int)f2bf(f.x) | ((unsigned int)f2bf(f.y) << 16);
            hb[(i + u) * 2 + 1] = (unsigned int)f2bf(f.z) | ((unsigned int)f2bf(f.w) << 16);
        }
    } else {
        const int blk = blockIdx.y * 32 + blockIdx.x;
        const int i = blk * 256 + threadIdx.x;
        if (i < 1536) bqkv[i] = i < 512 ? bq[i] : (i < 1024 ? bk[i - 512] : bv[i - 1024]);
        if (i < 2048) st[i] = 0.0f;
    }
}

// ---------------------------------------------------------------------------
// Sparse attention v5 with INLINE adjacency build. Block = node, 4 waves.
// Phase A: wave w ballot-compacts cols w*1024..+1024 of this node's A-row
// (2-pass: count -> LDS prefix -> write). Overlaps the 64MB A scan with the
// latency-bound gather phase and removes the build_adj dispatch + adj/deg
// round-trip.
// Phase B: v4 structure — wave wv does heads wv and wv+4 in the same loops,
// uint4 score gathers (8 nbrs/iter), uint2 accum gathers (4 nbrs/iter),
// 1-deep prefetch. NO bulk K/V LDS staging (v3 proved that's the 1-block/CU
// occupancy cliff: 123us vs 65us).
// ---------------------------------------------------------------------------
__global__ __launch_bounds__(256) void sparse_attn5(
    const float* __restrict__ A, const unsigned short* __restrict__ qkv,
    unsigned short* __restrict__ o)
{
    const int n = blockIdx.x;
    const int tid = threadIdx.x;
    const int wv = tid >> 6, lane = tid & 63;

    __shared__ int s_idx[MAXD];
    __shared__ float s_p[8][MAXD];
    __shared__ int s_cnt[4];

    // ---- Phase A: inline adjacency ----
    const float4* r4 = (const float4*)(A + (size_t)n * N_NODES);
    float4 av[4];
    #pragma unroll
    for (int t = 0; t < 4; ++t)
        av[t] = r4[wv * 256 + t * 64 + lane];

    const unsigned long long lt = (1ull << lane) - 1ull;
    int cnt = 0;
    #pragma unroll
    for (int t = 0; t < 4; ++t) {
        #pragma unroll
        for (int b = 0; b < 4; ++b) {
            float vb = (b == 0) ? av[t].x : (b == 1) ? av[t].y : (b == 2) ? av[t].z : av[t].w;
            cnt += __popcll(__ballot(vb > 0.0f));
        }
    }
    if (lane == 0) s_cnt[wv] = cnt;
    __syncthreads();
    int base = 0, total = 0;
    #pragma unroll
    for (int w = 0; w < 4; ++w) {
        if (w < wv) base += s_cnt[w];
        total += s_cnt[w];
    }
    const int d = total < MAXD ? total : MAXD;
    #pragma unroll
    for (int t = 0; t < 4; ++t) {
        #pragma unroll
        for (int b = 0; b < 4; ++b) {
            float vb = (b == 0) ? av[t].x : (b == 1) ? av[t].y : (b == 2) ? av[t].z : av[t].w;
            unsigned long long m = __ballot(vb > 0.0f);
            if (vb > 0.0f) {
                int p = base + __popcll(m & lt);
                if (p < MAXD) s_idx[p] = wv * 1024 + t * 256 + lane * 4 + b;
            }
            base += __popcll(m);
        }
    }
    __syncthreads();

    // ---- Phase B: attention ----
    const int jl = lane >> 3;      // neighbor sub-index (score), 0..7
    const int dgs = lane & 7;      // dim-group of 8 (score)
    const int jl2 = lane >> 4;     // neighbor sub-index (accum), 0..3
    const int dga = lane & 15;     // dim-group of 4 (accum)
    const int h0 = wv, h1 = wv + 4;

    const unsigned short* qp = qkv + (size_t)n * 1536 + dgs * 8;
    uint4 qa = *(const uint4*)(qp + h0 * 64);
    uint4 qb = *(const uint4*)(qp + h1 * 64);
    const float a0 = blo(qa.x), a1 = bhi(qa.x), a2 = blo(qa.y), a3 = bhi(qa.y);
    const float a4 = blo(qa.z), a5 = bhi(qa.z), a6 = blo(qa.w), a7 = bhi(qa.w);
    const float b0 = blo(qb.x), b1 = bhi(qb.x), b2 = blo(qb.y), b3 = bhi(qb.y);
    const float b4 = blo(qb.z), b5 = bhi(qb.z), b6 = blo(qb.w), b7 = bhi(qb.w);

    uint4 ka = {0, 0, 0, 0}, kb = {0, 0, 0, 0};
    if (jl < d) {
        const unsigned short* p = qkv + (size_t)s_idx[jl] * 1536 + 512 + dgs * 8;
        ka = *(const uint4*)(p + h0 * 64);
        kb = *(const uint4*)(p + h1 * 64);
    }
    for (int j0 = 0; j0 < d; j0 += 8) {
        const uint4 ca = ka, cb = kb;
        const int jn = j0 + 8 + jl;
        if (jn < d) {
            const unsigned short* p = qkv + (size_t)s_idx[jn] * 1536 + 512 + dgs * 8;
            ka = *(const uint4*)(p + h0 * 64);
            kb = *(const uint4*)(p + h1 * 64);
        }
        const int jc = j0 + jl;
        float s0 = 0.f, s1 = 0.f;
        if (jc < d) {
            s0 = a0 * blo(ca.x) + a1 * bhi(ca.x) + a2 * blo(ca.y) + a3 * bhi(ca.y)
               + a4 * blo(ca.z) + a5 * bhi(ca.z) + a6 * blo(ca.w) + a7 * bhi(ca.w);
            s1 = b0 * blo(cb.x) + b1 * bhi(cb.x) + b2 * blo(cb.y) + b3 * bhi(cb.y)
               + b4 * blo(cb.z) + b5 * bhi(cb.z) + b6 * blo(cb.w) + b7 * bhi(cb.w);
        }
        s0 += __shfl_xor(s0, 1); s1 += __shfl_xor(s1, 1);
        s0 += __shfl_xor(s0, 2); s1 += __shfl_xor(s1, 2);
        s0 += __shfl_xor(s0, 4); s1 += __shfl_xor(s1, 4);
        if (dgs == 0 && jc < d) {
            s_p[h0][jc] = s0 * 0.125f;    // 1/sqrt(64)
            s_p[h1][jc] = s1 * 0.125f;
        }
    }

    float inv0, inv1;
    #pragma unroll
    for (int hh = 0; hh < 2; ++hh) {
        float* sp = s_p[hh ? h1 : h0];
        float mx = -1e30f;
        for (int j = lane; j < d; j += 64) mx = fmaxf(mx, sp[j]);
        #pragma unroll
        for (int off = 32; off; off >>= 1) mx = fmaxf(mx, __shfl_xor(mx, off));
        float sum = 0.f;
        for (int j = lane; j < d; j += 64) {
            float e = __expf(sp[j] - mx);
            sp[j] = e;
            sum += e;
        }
        #pragma unroll
        for (int off = 32; off; off >>= 1) sum += __shfl_xor(sum, off);
        if (hh) inv1 = 1.0f / sum; else inv0 = 1.0f / sum;
    }

    float x0 = 0.f, x1 = 0.f, x2 = 0.f, x3 = 0.f;
    float y0 = 0.f, y1 = 0.f, y2 = 0.f, y3 = 0.f;
    uint2 va = {0, 0}, vb = {0, 0};
    if (jl2 < d) {
        const unsigned short* p = qkv + (size_t)s_idx[jl2] * 1536 + 1024 + dga * 4;
        va = *(const uint2*)(p + h0 * 64);
        vb = *(const uint2*)(p + h1 * 64);
    }
    for (int j0 = 0; j0 < d; j0 += 4) {
        const uint2 ca = va, cb = vb;
        const int jn = j0 + 4 + jl2;
        if (jn < d) {
            const unsigned short* p = qkv + (size_t)s_idx[jn] * 1536 + 1024 + dga * 4;
            va = *(const uint2*)(p + h0 * 64);
            vb = *(const uint2*)(p + h1 * 64);
        }
        const int jc = j0 + jl2;
        if (jc < d) {
            const float p0 = s_p[h0][jc], p1 = s_p[h1][jc];
            x0 += p0 * blo(ca.x); x1 += p0 * bhi(ca.x);
            x2 += p0 * blo(ca.y); x3 += p0 * bhi(ca.y);
            y0 += p1 * blo(cb.x); y1 += p1 * bhi(cb.x);
            y2 += p1 * blo(cb.y); y3 += p1 * bhi(cb.y);
        }
    }
    x0 += __shfl_xor(x0, 16); x0 += __shfl_xor(x0, 32);
    x1 += __shfl_xor(x1, 16); x1 += __shfl_xor(x1, 32);
    x2 += __shfl_xor(x2, 16); x2 += __shfl_xor(x2, 32);
    x3 += __shfl_xor(x3, 16); x3 += __shfl_xor(x3, 32);
    y0 += __shfl_xor(y0, 16); y0 += __shfl_xor(y0, 32);
    y1 += __shfl_xor(y1, 16); y1 += __shfl_xor(y1, 32);
    y2 += __shfl_xor(y2, 16); y2 += __shfl_xor(y2, 32);
    y3 += __shfl_xor(y3, 16); y3 += __shfl_xor(y3, 32);
    if (jl2 == 0) {
        uint2 w0, w1;
        w0.x = (unsigned int)f2bf(x0 * inv0) | ((unsigned int)f2bf(x1 * inv0) << 16);
        w0.y = (unsigned int)f2bf(x2 * inv0) | ((unsigned int)f2bf(x3 * inv0) << 16);
        w1.x = (unsigned int)f2bf(y0 * inv1) | ((unsigned int)f2bf(y1 * inv1) << 16);
        w1.y = (unsigned int)f2bf(y2 * inv1) | ((unsigned int)f2bf(y3 * inv1) << 16);
        *(uint2*)(o + (size_t)n * 512 + h0 * 64 + dga * 4) = w0;
        *(uint2*)(o + (size_t)n * 512 + h1 * 64 + dga * 4) = w1;
    }
}

// ---------------------------------------------------------------------------
// BatchNorm apply, float4 (stats fused in the preceding GEMM epilogue)
// ---------------------------------------------------------------------------
__global__ __launch_bounds__(256) void bn_apply4(
    const float4* __restrict__ x, const float* __restrict__ sum,
    const float* __restrict__ sumsq, const float* __restrict__ g,
    const float* __restrict__ b, float4* __restrict__ yf,
    uint2* __restrict__ yb)
{
    const int i = blockIdx.x * 256 + threadIdx.x;   // float4 index over N*HID/4
    const int c4 = i & 127;
    const float4 s4 = ((const float4*)sum)[c4];
    const float4 q4 = ((const float4*)sumsq)[c4];
    const float4 g4 = ((const float4*)g)[c4];
    const float4 b4 = ((const float4*)b)[c4];
    const float4 xv = x[i];
    const float kN = 1.0f / N_NODES;
    float4 r;
    { float m = s4.x * kN; r.x = g4.x * (xv.x - m) * rsqrtf(q4.x * kN - m * m + EPS) + b4.x; }
    { float m = s4.y * kN; r.y = g4.y * (xv.y - m) * rsqrtf(q4.y * kN - m * m + EPS) + b4.y; }
    { float m = s4.z * kN; r.z = g4.z * (xv.z - m) * rsqrtf(q4.z * kN - m * m + EPS) + b4.z; }
    { float m = s4.w * kN; r.w = g4.w * (xv.w - m) * rsqrtf(q4.w * kN - m * m + EPS) + b4.w; }
    yf[i] = r;
    if (yb) {
        uint2 p;
        p.x = (unsigned int)f2bf(r.x) | ((unsigned int)f2bf(r.y) << 16);
        p.y = (unsigned int)f2bf(r.z) | ((unsigned int)f2bf(r.w) << 16);
        yb[i] = p;
    }
}

// ---------------------------------------------------------------------------

extern "C" void kernel_launch(void* const* d_in, const int* in_sizes, int n_in,
                              void* d_out, int out_size, void* d_ws, size_t ws_size,
                              hipStream_t stream)
{
    const float* A   = (const float*)d_in[0];
    const float* h   = (const float*)d_in[1];
    const float* Wq  = (const float*)d_in[2];
    const float* bq  = (const float*)d_in[3];
    const float* Wk  = (const float*)d_in[4];
    const float* bk  = (const float*)d_in[5];
    const float* Wv  = (const float*)d_in[6];
    const float* bv  = (const float*)d_in[7];
    const float* Wo  = (const float*)d_in[8];
    const float* bo  = (const float*)d_in[9];
    const float* g1  = (const float*)d_in[10];
    const float* b1g = (const float*)d_in[11];
    const float* g2  = (const float*)d_in[12];
    const float* b2g = (const float*)d_in[13];
    const float* W1  = (const float*)d_in[14];
    const float* b1  = (const float*)d_in[15];
    const float* W2  = (const float*)d_in[16];
    const float* b2  = (const float*)d_in[17];
    float* out = (float*)d_out;

    float* ws = (float*)d_ws;
    unsigned short* hb    = (unsigned short*)(ws);               // 4096x512 bf16
    unsigned short* qkvb  = (unsigned short*)(ws + 1048576);     // 4096x1536 bf16
    unsigned short* o_bf  = (unsigned short*)(ws + 4194304);     // 4096x512 bf16
    unsigned short* wqkvT = (unsigned short*)(ws + 5242880);     // 1536x512 bf16
    unsigned short* woT   = (unsigned short*)(ws + 5636096);     // 512x512 bf16
    unsigned short* w1T   = (unsigned short*)(ws + 5767168);     // 1024x512 bf16
    unsigned short* w2T   = (unsigned short*)(ws + 6029312);     // 512x1024 bf16
    unsigned short* t_b   = (unsigned short*)(ws + 6291456);     // 4096x1024 bf16
    float* x1   = ws + 8388608;                                   // 4096x512 f32
    float* x2   = ws + 10485760;                                  // 4096x512 f32
    unsigned short* xb1_b = (unsigned short*)(ws + 12582912);    // 4096x512 bf16
    float* bqkv = ws + 13631488;                                  // 1536
    float* st   = ws + 13633024;                                  // 2048

    // --- fused prep (6 transposes + h->bf16 + bias concat + stat zero) ---
    prep_all<<<dim3(32, 32, 8), dim3(256), 0, stream>>>(
        Wq, Wk, Wv, Wo, W1, W2, h, bq, bk, bv,
        wqkvT, woT, w1T, w2T, (unsigned int*)hb, bqkv, st);

    // --- fused QKV projection ---
    gemm_bf16<128, 0><<<dim3(12, 32), dim3(256), 0, stream>>>(
        hb, wqkvT, bqkv, nullptr, nullptr, qkvb, nullptr, nullptr, 512, 1536);

    // --- sparse masked attention (inline adjacency) ---
    sparse_attn5<<<dim3(N_NODES), dim3(256), 0, stream>>>(A, qkvb, o_bf);

    // --- O projection + residual + fused BN1 stats ---
    gemm_bf16<64, 2><<<dim3(8, 32), dim3(256), 0, stream>>>(
        o_bf, woT, bo, h, x1, nullptr, st, st + 512, 512, 512);

    // --- BN1 apply ---
    bn_apply4<<<dim3(2048), dim3(256), 0, stream>>>(
        (const float4*)x1, st, st + 512, g1, b1g, (float4*)x1, (uint2*)xb1_b);

    // --- FFN ---
    gemm_bf16<128, 1><<<dim3(8, 32), dim3(256), 0, stream>>>(
        xb1_b, w1T, b1, nullptr, nullptr, t_b, nullptr, nullptr, 512, 1024);
    gemm_bf16<64, 2><<<dim3(8, 32), dim3(256), 0, stream>>>(
        t_b, w2T, b2, x1, x2, nullptr, st + 1024, st + 1536, 1024, 512);

    // --- BN2 apply -> out ---
    bn_apply4<<<dim3(2048), dim3(256), 0, stream>>>(
        (const float4*)x2, st + 1024, st + 1536, g2, b2g, (float4*)out, nullptr);

    (void)in_sizes; (void)n_in; (void)out_size; (void)ws_size;
}

// Round 6
// 232.904 us; speedup vs baseline: 2.5793x; 1.0413x over previous
//
#include <hip/hip_runtime.h>

#define N_NODES 4096
#define HID 512
#define HEADS 8
#define DH 64
#define EPS 1e-5f
#define MAXD 128

typedef __attribute__((ext_vector_type(8))) short bf16x8;
typedef __attribute__((ext_vector_type(4))) float f32x4;

__device__ __forceinline__ unsigned short f2bf(float f) {
    unsigned int u = __float_as_uint(f);
    unsigned int r = (u + 0x7FFFu + ((u >> 16) & 1u)) >> 16;   // RNE
    return (unsigned short)r;
}
__device__ __forceinline__ float blo(unsigned int u) {        // low bf16 -> f32
    return __uint_as_float(u << 16);
}
__device__ __forceinline__ float bhi(unsigned int u) {        // high bf16 -> f32
    return __uint_as_float(u & 0xffff0000u);
}

__device__ __forceinline__ void gld_lds16(const void* g, void* l) {
    __builtin_amdgcn_global_load_lds(
        (const __attribute__((address_space(1))) unsigned int*)g,
        (__attribute__((address_space(3))) unsigned int*)l, 16, 0, 0);
}

// ---------------------------------------------------------------------------
// bf16 MFMA GEMM: C[M x Nc] = X[M x K] @ W^T  (Wt[Nc][K] K-major)
// TM x 64 tile, BK=64, 256 threads = 4 waves stacked on M (WM = TM/64 mfma
// row-tiles per wave). Tile-N fixed at 64 so every GEMM launches >=512
// blocks (>=2/CU) — at 1 block/CU the barrier drain stalls the whole CU
// (R5 lesson: 256-block GEMMs ran at 12.5% occupancy).
// Swizzle: global k-chunk (tid&7)^(srow&7) -> LDS slot s of row r holds
// chunk s^(r&7); read slot (half*4+lq)^(lc&7) -> conflict-free b128
// (0 SQ_LDS_BANK_CONFLICT measured in R5).
// EPI: 0 bias->bf16 ; 1 bias+relu->bf16 ; 2 bias+res(f32)->f32 + stats ;
//      3 bias+res(bf16)->f32 + stats
// ---------------------------------------------------------------------------
template<int TM, int EPI>
__global__ __launch_bounds__(256) void gemm_bf16(
    const unsigned short* __restrict__ Xb, const unsigned short* __restrict__ Wt,
    const float* __restrict__ bias, const float* __restrict__ res,
    const unsigned short* __restrict__ resb,
    float* __restrict__ outf, unsigned short* __restrict__ outb,
    float* __restrict__ sum, float* __restrict__ sumsq,
    int K, int Nc)
{
    constexpr int WM = TM / 64;                      // 2 (TM=128) or 1 (TM=64)
    __shared__ __align__(16) unsigned short As[TM * 64];
    __shared__ __align__(16) unsigned short Bs[64 * 64];

    const int tid = threadIdx.x;
    const int lane = tid & 63;
    const int wv = tid >> 6;
    const int m0 = blockIdx.y * TM, n0 = blockIdx.x * 64;
    const int lc = lane & 15, lq = lane >> 4;
    const int rowbase = wv * (WM * 16);

    const int srow = tid >> 3;                       // 0..31
    const int schunk = (tid & 7) ^ (srow & 7);       // swizzled global k-chunk
    unsigned short* ldsA = As + tid * 8;
    unsigned short* ldsB = Bs + tid * 8;
    const int rs0 = lq ^ (lc & 7);
    const int rs1 = (4 + lq) ^ (lc & 7);

    f32x4 acc[WM][4] = {};

    for (int k0 = 0; k0 < K; k0 += 64) {
        const unsigned short* gA = Xb + (size_t)(m0 + srow) * K + k0 + schunk * 8;
        const unsigned short* gB = Wt + (size_t)(n0 + srow) * K + k0 + schunk * 8;
        #pragma unroll
        for (int p = 0; p < TM / 32; ++p)
            gld_lds16(gA + (size_t)(p * 32) * K, ldsA + p * 2048);
        #pragma unroll
        for (int p = 0; p < 2; ++p)
            gld_lds16(gB + (size_t)(p * 32) * K, ldsB + p * 2048);
        __syncthreads();

        #pragma unroll
        for (int hh = 0; hh < 2; ++hh) {
            const int rs = hh ? rs1 : rs0;
            bf16x8 af[WM], bfr[4];
            #pragma unroll
            for (int i = 0; i < WM; ++i)
                af[i] = *(const bf16x8*)&As[(rowbase + i * 16 + lc) * 64 + rs * 8];
            #pragma unroll
            for (int j = 0; j < 4; ++j)
                bfr[j] = *(const bf16x8*)&Bs[(j * 16 + lc) * 64 + rs * 8];
            #pragma unroll
            for (int i = 0; i < WM; ++i)
                #pragma unroll
                for (int j = 0; j < 4; ++j)
                    acc[i][j] = __builtin_amdgcn_mfma_f32_16x16x32_bf16(af[i], bfr[j], acc[i][j], 0, 0, 0);
        }
        __syncthreads();
    }

    float cs[4] = {}, css[4] = {};
    #pragma unroll
    for (int i = 0; i < WM; ++i) {
        #pragma unroll
        for (int j = 0; j < 4; ++j) {
            const int gr0 = m0 + rowbase + i * 16 + lq * 4;
            const int gc = n0 + j * 16 + lc;
            const float bi = bias[gc];
            #pragma unroll
            for (int r = 0; r < 4; ++r) {
                float val = acc[i][j][r] + bi;
                size_t off = (size_t)(gr0 + r) * Nc + gc;
                if (EPI == 0)      outb[off] = f2bf(val);
                else if (EPI == 1) outb[off] = f2bf(fmaxf(val, 0.f));
                else {
                    if (EPI == 2) val += res[off];
                    else          val += blo((unsigned int)resb[off]);
                    outf[off] = val;
                    cs[j] += val; css[j] += val * val;
                }
            }
        }
    }
    if (EPI >= 2) {
        #pragma unroll
        for (int j = 0; j < 4; ++j) {
            float s = cs[j], ss = css[j];
            s += __shfl_xor(s, 16); s += __shfl_xor(s, 32);
            ss += __shfl_xor(ss, 16); ss += __shfl_xor(ss, 32);
            if (lq == 0) {
                const int gc = n0 + j * 16 + lc;
                atomicAdd(&sum[gc], s);
                atomicAdd(&sumsq[gc], ss);
            }
        }
    }
}

// ---------------------------------------------------------------------------
// Fused prep: z=0..5 weight transposes, z=6 h->bf16, z=7 bias concat + zero
// ---------------------------------------------------------------------------
__global__ __launch_bounds__(256) void prep_all(
    const float* __restrict__ Wq, const float* __restrict__ Wk,
    const float* __restrict__ Wv, const float* __restrict__ Wo,
    const float* __restrict__ W1, const float* __restrict__ W2,
    const float* __restrict__ h,
    const float* __restrict__ bq, const float* __restrict__ bk,
    const float* __restrict__ bv,
    unsigned short* __restrict__ wqkvT, unsigned short* __restrict__ woT,
    unsigned short* __restrict__ w1T, unsigned short* __restrict__ w2T,
    unsigned int* __restrict__ hb, float* __restrict__ bqkv,
    float* __restrict__ st)
{
    const int z = blockIdx.z;
    if (z < 6) {
        const float* in; unsigned short* out; int R, C;
        switch (z) {
            case 0: in = Wq; out = wqkvT;          R = 512;  C = 512;  break;
            case 1: in = Wk; out = wqkvT + 262144; R = 512;  C = 512;  break;
            case 2: in = Wv; out = wqkvT + 524288; R = 512;  C = 512;  break;
            case 3: in = Wo; out = woT;            R = 512;  C = 512;  break;
            case 4: in = W1; out = w1T;            R = 512;  C = 1024; break;
            default: in = W2; out = w2T;           R = 1024; C = 512;  break;
        }
        const int bc = blockIdx.x * 32, br = blockIdx.y * 32;
        if (bc >= C || br >= R) return;
        __shared__ float tile[32][33];
        const int tx = threadIdx.x & 31, ty = threadIdx.x >> 5;
        #pragma unroll
        for (int r = ty; r < 32; r += 8)
            tile[r][tx] = in[(size_t)(br + r) * C + bc + tx];
        __syncthreads();
        #pragma unroll
        for (int r = ty; r < 32; r += 8)
            out[(size_t)(bc + r) * R + br + tx] = f2bf(tile[tx][r]);
    } else if (z == 6) {
        const int blk = blockIdx.y * 32 + blockIdx.x;
        const int i = blk * 512 + threadIdx.x * 2;   // float4 index (524288 total)
        const float4* in4 = (const float4*)h;
        #pragma unroll
        for (int u = 0; u < 2; ++u) {
            float4 f = in4[i + u];
            hb[(i + u) * 2]     = (unsigned int)f2bf(f.x) | ((unsigned int)f2bf(f.y) << 16);
            hb[(i + u) * 2 + 1] = (unsigned int)f2bf(f.z) | ((unsigned int)f2bf(f.w) << 16);
        }
    } else {
        const int blk = blockIdx.y * 32 + blockIdx.x;
        const int i = blk * 256 + threadIdx.x;
        if (i < 1536) bqkv[i] = i < 512 ? bq[i] : (i < 1024 ? bk[i - 512] : bv[i - 1024]);
        if (i < 2048) st[i] = 0.0f;
    }
}

// ---------------------------------------------------------------------------
// Sparse attention v5 (unchanged from R5: 48us, 0 conflicts, occupancy 65%).
// Inline adjacency build + dual-head gather loops with 1-deep prefetch.
// NO bulk K/V LDS staging (v3's 1-block/CU cliff: 123us vs 65us).
// ---------------------------------------------------------------------------
__global__ __launch_bounds__(256) void sparse_attn5(
    const float* __restrict__ A, const unsigned short* __restrict__ qkv,
    unsigned short* __restrict__ o)
{
    const int n = blockIdx.x;
    const int tid = threadIdx.x;
    const int wv = tid >> 6, lane = tid & 63;

    __shared__ int s_idx[MAXD];
    __shared__ float s_p[8][MAXD];
    __shared__ int s_cnt[4];

    // ---- Phase A: inline adjacency ----
    const float4* r4 = (const float4*)(A + (size_t)n * N_NODES);
    float4 av[4];
    #pragma unroll
    for (int t = 0; t < 4; ++t)
        av[t] = r4[wv * 256 + t * 64 + lane];

    const unsigned long long lt = (1ull << lane) - 1ull;
    int cnt = 0;
    #pragma unroll
    for (int t = 0; t < 4; ++t) {
        #pragma unroll
        for (int b = 0; b < 4; ++b) {
            float vb = (b == 0) ? av[t].x : (b == 1) ? av[t].y : (b == 2) ? av[t].z : av[t].w;
            cnt += __popcll(__ballot(vb > 0.0f));
        }
    }
    if (lane == 0) s_cnt[wv] = cnt;
    __syncthreads();
    int base = 0, total = 0;
    #pragma unroll
    for (int w = 0; w < 4; ++w) {
        if (w < wv) base += s_cnt[w];
        total += s_cnt[w];
    }
    const int d = total < MAXD ? total : MAXD;
    #pragma unroll
    for (int t = 0; t < 4; ++t) {
        #pragma unroll
        for (int b = 0; b < 4; ++b) {
            float vb = (b == 0) ? av[t].x : (b == 1) ? av[t].y : (b == 2) ? av[t].z : av[t].w;
            unsigned long long m = __ballot(vb > 0.0f);
            if (vb > 0.0f) {
                int p = base + __popcll(m & lt);
                if (p < MAXD) s_idx[p] = wv * 1024 + t * 256 + lane * 4 + b;
            }
            base += __popcll(m);
        }
    }
    __syncthreads();

    // ---- Phase B: attention ----
    const int jl = lane >> 3;
    const int dgs = lane & 7;
    const int jl2 = lane >> 4;
    const int dga = lane & 15;
    const int h0 = wv, h1 = wv + 4;

    const unsigned short* qp = qkv + (size_t)n * 1536 + dgs * 8;
    uint4 qa = *(const uint4*)(qp + h0 * 64);
    uint4 qb = *(const uint4*)(qp + h1 * 64);
    const float a0 = blo(qa.x), a1 = bhi(qa.x), a2 = blo(qa.y), a3 = bhi(qa.y);
    const float a4 = blo(qa.z), a5 = bhi(qa.z), a6 = blo(qa.w), a7 = bhi(qa.w);
    const float b0 = blo(qb.x), b1 = bhi(qb.x), b2 = blo(qb.y), b3 = bhi(qb.y);
    const float b4 = blo(qb.z), b5 = bhi(qb.z), b6 = blo(qb.w), b7 = bhi(qb.w);

    uint4 ka = {0, 0, 0, 0}, kb = {0, 0, 0, 0};
    if (jl < d) {
        const unsigned short* p = qkv + (size_t)s_idx[jl] * 1536 + 512 + dgs * 8;
        ka = *(const uint4*)(p + h0 * 64);
        kb = *(const uint4*)(p + h1 * 64);
    }
    for (int j0 = 0; j0 < d; j0 += 8) {
        const uint4 ca = ka, cb = kb;
        const int jn = j0 + 8 + jl;
        if (jn < d) {
            const unsigned short* p = qkv + (size_t)s_idx[jn] * 1536 + 512 + dgs * 8;
            ka = *(const uint4*)(p + h0 * 64);
            kb = *(const uint4*)(p + h1 * 64);
        }
        const int jc = j0 + jl;
        float s0 = 0.f, s1 = 0.f;
        if (jc < d) {
            s0 = a0 * blo(ca.x) + a1 * bhi(ca.x) + a2 * blo(ca.y) + a3 * bhi(ca.y)
               + a4 * blo(ca.z) + a5 * bhi(ca.z) + a6 * blo(ca.w) + a7 * bhi(ca.w);
            s1 = b0 * blo(cb.x) + b1 * bhi(cb.x) + b2 * blo(cb.y) + b3 * bhi(cb.y)
               + b4 * blo(cb.z) + b5 * bhi(cb.z) + b6 * blo(cb.w) + b7 * bhi(cb.w);
        }
        s0 += __shfl_xor(s0, 1); s1 += __shfl_xor(s1, 1);
        s0 += __shfl_xor(s0, 2); s1 += __shfl_xor(s1, 2);
        s0 += __shfl_xor(s0, 4); s1 += __shfl_xor(s1, 4);
        if (dgs == 0 && jc < d) {
            s_p[h0][jc] = s0 * 0.125f;
            s_p[h1][jc] = s1 * 0.125f;
        }
    }

    float inv0, inv1;
    #pragma unroll
    for (int hh = 0; hh < 2; ++hh) {
        float* sp = s_p[hh ? h1 : h0];
        float mx = -1e30f;
        for (int j = lane; j < d; j += 64) mx = fmaxf(mx, sp[j]);
        #pragma unroll
        for (int off = 32; off; off >>= 1) mx = fmaxf(mx, __shfl_xor(mx, off));
        float sum = 0.f;
        for (int j = lane; j < d; j += 64) {
            float e = __expf(sp[j] - mx);
            sp[j] = e;
            sum += e;
        }
        #pragma unroll
        for (int off = 32; off; off >>= 1) sum += __shfl_xor(sum, off);
        if (hh) inv1 = 1.0f / sum; else inv0 = 1.0f / sum;
    }

    float x0 = 0.f, x1 = 0.f, x2 = 0.f, x3 = 0.f;
    float y0 = 0.f, y1 = 0.f, y2 = 0.f, y3 = 0.f;
    uint2 va = {0, 0}, vb = {0, 0};
    if (jl2 < d) {
        const unsigned short* p = qkv + (size_t)s_idx[jl2] * 1536 + 1024 + dga * 4;
        va = *(const uint2*)(p + h0 * 64);
        vb = *(const uint2*)(p + h1 * 64);
    }
    for (int j0 = 0; j0 < d; j0 += 4) {
        const uint2 ca = va, cb = vb;
        const int jn = j0 + 4 + jl2;
        if (jn < d) {
            const unsigned short* p = qkv + (size_t)s_idx[jn] * 1536 + 1024 + dga * 4;
            va = *(const uint2*)(p + h0 * 64);
            vb = *(const uint2*)(p + h1 * 64);
        }
        const int jc = j0 + jl2;
        if (jc < d) {
            const float p0 = s_p[h0][jc], p1 = s_p[h1][jc];
            x0 += p0 * blo(ca.x); x1 += p0 * bhi(ca.x);
            x2 += p0 * blo(ca.y); x3 += p0 * bhi(ca.y);
            y0 += p1 * blo(cb.x); y1 += p1 * bhi(cb.x);
            y2 += p1 * blo(cb.y); y3 += p1 * bhi(cb.y);
        }
    }
    x0 += __shfl_xor(x0, 16); x0 += __shfl_xor(x0, 32);
    x1 += __shfl_xor(x1, 16); x1 += __shfl_xor(x1, 32);
    x2 += __shfl_xor(x2, 16); x2 += __shfl_xor(x2, 32);
    x3 += __shfl_xor(x3, 16); x3 += __shfl_xor(x3, 32);
    y0 += __shfl_xor(y0, 16); y0 += __shfl_xor(y0, 32);
    y1 += __shfl_xor(y1, 16); y1 += __shfl_xor(y1, 32);
    y2 += __shfl_xor(y2, 16); y2 += __shfl_xor(y2, 32);
    y3 += __shfl_xor(y3, 16); y3 += __shfl_xor(y3, 32);
    if (jl2 == 0) {
        uint2 w0, w1;
        w0.x = (unsigned int)f2bf(x0 * inv0) | ((unsigned int)f2bf(x1 * inv0) << 16);
        w0.y = (unsigned int)f2bf(x2 * inv0) | ((unsigned int)f2bf(x3 * inv0) << 16);
        w1.x = (unsigned int)f2bf(y0 * inv1) | ((unsigned int)f2bf(y1 * inv1) << 16);
        w1.y = (unsigned int)f2bf(y2 * inv1) | ((unsigned int)f2bf(y3 * inv1) << 16);
        *(uint2*)(o + (size_t)n * 512 + h0 * 64 + dga * 4) = w0;
        *(uint2*)(o + (size_t)n * 512 + h1 * 64 + dga * 4) = w1;
    }
}

// ---------------------------------------------------------------------------
// BatchNorm apply, float4 (stats fused in the preceding GEMM epilogue).
// yf / yb each optional (uniform null check).
// ---------------------------------------------------------------------------
__global__ __launch_bounds__(256) void bn_apply4(
    const float4* __restrict__ x, const float* __restrict__ sum,
    const float* __restrict__ sumsq, const float* __restrict__ g,
    const float* __restrict__ b, float4* __restrict__ yf,
    uint2* __restrict__ yb)
{
    const int i = blockIdx.x * 256 + threadIdx.x;
    const int c4 = i & 127;
    const float4 s4 = ((const float4*)sum)[c4];
    const float4 q4 = ((const float4*)sumsq)[c4];
    const float4 g4 = ((const float4*)g)[c4];
    const float4 b4 = ((const float4*)b)[c4];
    const float4 xv = x[i];
    const float kN = 1.0f / N_NODES;
    float4 r;
    { float m = s4.x * kN; r.x = g4.x * (xv.x - m) * rsqrtf(q4.x * kN - m * m + EPS) + b4.x; }
    { float m = s4.y * kN; r.y = g4.y * (xv.y - m) * rsqrtf(q4.y * kN - m * m + EPS) + b4.y; }
    { float m = s4.z * kN; r.z = g4.z * (xv.z - m) * rsqrtf(q4.z * kN - m * m + EPS) + b4.z; }
    { float m = s4.w * kN; r.w = g4.w * (xv.w - m) * rsqrtf(q4.w * kN - m * m + EPS) + b4.w; }
    if (yf) yf[i] = r;
    if (yb) {
        uint2 p;
        p.x = (unsigned int)f2bf(r.x) | ((unsigned int)f2bf(r.y) << 16);
        p.y = (unsigned int)f2bf(r.z) | ((unsigned int)f2bf(r.w) << 16);
        yb[i] = p;
    }
}

// ---------------------------------------------------------------------------

extern "C" void kernel_launch(void* const* d_in, const int* in_sizes, int n_in,
                              void* d_out, int out_size, void* d_ws, size_t ws_size,
                              hipStream_t stream)
{
    const float* A   = (const float*)d_in[0];
    const float* h   = (const float*)d_in[1];
    const float* Wq  = (const float*)d_in[2];
    const float* bq  = (const float*)d_in[3];
    const float* Wk  = (const float*)d_in[4];
    const float* bk  = (const float*)d_in[5];
    const float* Wv  = (const float*)d_in[6];
    const float* bv  = (const float*)d_in[7];
    const float* Wo  = (const float*)d_in[8];
    const float* bo  = (const float*)d_in[9];
    const float* g1  = (const float*)d_in[10];
    const float* b1g = (const float*)d_in[11];
    const float* g2  = (const float*)d_in[12];
    const float* b2g = (const float*)d_in[13];
    const float* W1  = (const float*)d_in[14];
    const float* b1  = (const float*)d_in[15];
    const float* W2  = (const float*)d_in[16];
    const float* b2  = (const float*)d_in[17];
    float* out = (float*)d_out;

    float* ws = (float*)d_ws;
    unsigned short* hb    = (unsigned short*)(ws);               // 4096x512 bf16
    unsigned short* qkvb  = (unsigned short*)(ws + 1048576);     // 4096x1536 bf16
    unsigned short* o_bf  = (unsigned short*)(ws + 4194304);     // 4096x512 bf16
    unsigned short* wqkvT = (unsigned short*)(ws + 5242880);     // 1536x512 bf16
    unsigned short* woT   = (unsigned short*)(ws + 5636096);     // 512x512 bf16
    unsigned short* w1T   = (unsigned short*)(ws + 5767168);     // 1024x512 bf16
    unsigned short* w2T   = (unsigned short*)(ws + 6029312);     // 512x1024 bf16
    unsigned short* t_b   = (unsigned short*)(ws + 6291456);     // 4096x1024 bf16
    float* x1   = ws + 8388608;                                   // 4096x512 f32
    float* x2   = ws + 10485760;                                  // 4096x512 f32
    unsigned short* xb1_b = (unsigned short*)(ws + 12582912);    // 4096x512 bf16
    float* bqkv = ws + 13631488;                                  // 1536
    float* st   = ws + 13633024;                                  // 2048

    // --- fused prep ---
    prep_all<<<dim3(32, 32, 8), dim3(256), 0, stream>>>(
        Wq, Wk, Wv, Wo, W1, W2, h, bq, bk, bv,
        wqkvT, woT, w1T, w2T, (unsigned int*)hb, bqkv, st);

    // --- fused QKV projection: 768 blocks (3/CU) ---
    gemm_bf16<128, 0><<<dim3(24, 32), dim3(256), 0, stream>>>(
        hb, wqkvT, bqkv, nullptr, nullptr, nullptr, qkvb, nullptr, nullptr, 512, 1536);

    // --- sparse masked attention (inline adjacency) ---
    sparse_attn5<<<dim3(N_NODES), dim3(256), 0, stream>>>(A, qkvb, o_bf);

    // --- O projection + residual(h,f32) + BN1 stats: 512 blocks (2/CU) ---
    gemm_bf16<64, 2><<<dim3(8, 64), dim3(256), 0, stream>>>(
        o_bf, woT, bo, h, nullptr, x1, nullptr, st, st + 512, 512, 512);

    // --- BN1 apply -> bf16 only (FFN2 residual is bf16; saves fp32 RT) ---
    bn_apply4<<<dim3(2048), dim3(256), 0, stream>>>(
        (const float4*)x1, st, st + 512, g1, b1g, nullptr, (uint2*)xb1_b);

    // --- FFN1: 512 blocks (2/CU) ---
    gemm_bf16<128, 1><<<dim3(16, 32), dim3(256), 0, stream>>>(
        xb1_b, w1T, b1, nullptr, nullptr, nullptr, t_b, nullptr, nullptr, 512, 1024);

    // --- FFN2 + residual(xb1,bf16) + BN2 stats: 512 blocks (2/CU) ---
    gemm_bf16<64, 3><<<dim3(8, 64), dim3(256), 0, stream>>>(
        t_b, w2T, b2, nullptr, xb1_b, x2, nullptr, st + 1024, st + 1536, 1024, 512);

    // --- BN2 apply -> out ---
    bn_apply4<<<dim3(2048), dim3(256), 0, stream>>>(
        (const float4*)x2, st + 1024, st + 1536, g2, b2g, (float4*)out, nullptr);

    (void)in_sizes; (void)n_in; (void)out_size; (void)ws_size;
}